// Round 1
// 672.373 us; speedup vs baseline: 1.0742x; 1.0742x over previous
//
#include <hip/hip_runtime.h>
#include <math.h>

// ---------------------------------------------------------------------------
// MixedAttention: H=W=256, C=192, HEADS=6, NA: K=7 DIL=2 hd=32,
// stripe: WS=8 AWS=4 hs=16, 1024 windows.
// R8: MFMA neighborhood attention. Per parity plane, each wave owns a
// 16-query row strip; 7-row x 32-slot padded key window. QK^T and PV run on
// mfma_f32_16x16x32_bf16 (Q/K fragments straight from global planes, P
// through a tiny per-wave LDS transpose, V via short gathers). Flat softmax
// (identical math to R7), invalid slots masked to 0, clamped addresses keep
// garbage finite. Also: fold_wna_t gather fixed via one-shot qkv_w transpose
// (stride-576 gather was ~2GB of L2 traffic).
// ---------------------------------------------------------------------------

typedef unsigned short bf16_t;
typedef __attribute__((ext_vector_type(8))) short short8;   // MFMA A/B frag (8 bf16)
typedef __attribute__((ext_vector_type(4))) float f32x4;    // MFMA C/D frag

__device__ inline float bf2f(bf16_t v) { return __uint_as_float((unsigned)v << 16); }
__device__ inline bf16_t f2bf(float f) {
    unsigned u = __float_as_uint(f);
    unsigned r = (u + 0x7fffu + ((u >> 16) & 1u)) >> 16;   // RNE, finite inputs
    return (bf16_t)r;
}
__device__ inline float cvt(float v) { return v; }
__device__ inline float cvt(bf16_t v) { return bf2f(v); }
__device__ inline void sto(float* p, float v) { *p = v; }
__device__ inline void sto(bf16_t* p, float v) { *p = f2bf(v); }

// load 8 consecutive bf16 (16B aligned) -> 8 floats
__device__ inline void ld_bf8(const bf16_t* p, float* d) {
    uint4 r = *(const uint4*)p;
    d[0] = __uint_as_float(r.x << 16); d[1] = __uint_as_float(r.x & 0xffff0000u);
    d[2] = __uint_as_float(r.y << 16); d[3] = __uint_as_float(r.y & 0xffff0000u);
    d[4] = __uint_as_float(r.z << 16); d[5] = __uint_as_float(r.z & 0xffff0000u);
    d[6] = __uint_as_float(r.w << 16); d[7] = __uint_as_float(r.w & 0xffff0000u);
}
__device__ inline unsigned pk2(float a, float b) {
    return (unsigned)f2bf(a) | ((unsigned)f2bf(b) << 16);
}

// ---------------------------------------------------------------------------
// MFMA GEMM: C[M,N] = A[M,K]bf16 @ Bt[N,K]^T + bias. Tile 128x96, 4 waves,
// each wave 64x48 = 4x3 16x16 frags, K=192 fully unrolled, no LDS.
// NA=1: scatter-store into parity-split head planes:
//   ((which*6+h)*65536 + par*16384 + pi*128 + pj)*32 + d
// ---------------------------------------------------------------------------
template <int KD, int NA, typename TO>
__global__ __launch_bounds__(256) void mfma_gemm_k(
    const bf16_t* __restrict__ A, const bf16_t* __restrict__ Bt,
    const float* __restrict__ bias, TO* __restrict__ C,
    int lda, int ldb, int ldc)
{
    const int t = threadIdx.x;
    const int lane = t & 63, wave = t >> 6;
    const int wr = wave >> 1, wc = wave & 1;
    const int m0 = blockIdx.y * 128 + wr * 64;
    const int n0 = blockIdx.x * 96 + wc * 48;
    const int lm = lane & 15;
    const int q  = lane >> 4;

    f32x4 acc[4][3] = {};
    const bf16_t* ap = A + (size_t)(m0 + lm) * lda + q * 8;
    const bf16_t* bp = Bt + (size_t)(n0 + lm) * ldb + q * 8;

#pragma unroll
    for (int k0 = 0; k0 < KD; k0 += 32) {
        short8 af[4], bf[3];
#pragma unroll
        for (int mi = 0; mi < 4; mi++)
            af[mi] = *(const short8*)(ap + (size_t)(mi * 16) * lda + k0);
#pragma unroll
        for (int ni = 0; ni < 3; ni++)
            bf[ni] = *(const short8*)(bp + (size_t)(ni * 16) * ldb + k0);
#pragma unroll
        for (int mi = 0; mi < 4; mi++)
#pragma unroll
            for (int ni = 0; ni < 3; ni++)
                acc[mi][ni] = __builtin_amdgcn_mfma_f32_16x16x32_bf16(
                    af[mi], bf[ni], acc[mi][ni], 0, 0, 0);
    }

#pragma unroll
    for (int mi = 0; mi < 4; mi++) {
#pragma unroll
        for (int ni = 0; ni < 3; ni++) {
            int col = n0 + ni * 16 + lm;
            float bv = bias[col];
            if (NA) {
                int which = col / 192;
                int hh = (col % 192) / 32;
                int d  = col % 32;
                size_t pbase = ((size_t)which * 6 + hh) * ((size_t)65536 * 32) + d;
#pragma unroll
                for (int r = 0; r < 4; r++) {
                    int row = m0 + mi * 16 + q * 4 + r;
                    int ii = row >> 8, jj = row & 255;
                    int par = ((ii & 1) << 1) | (jj & 1);
                    int pix = par * 16384 + (ii >> 1) * 128 + (jj >> 1);
                    sto(&C[pbase + (size_t)pix * 32], acc[mi][ni][r] + bv);
                }
            } else {
#pragma unroll
                for (int r = 0; r < 4; r++) {
                    int row = m0 + mi * 16 + q * 4 + r;
                    sto(&C[(size_t)row * ldc + col], acc[mi][ni][r] + bv);
                }
            }
        }
    }
}

// x fp32 -> bf16, 8 elems/thread
__global__ __launch_bounds__(256) void cvt_bf16_k(
    const float* __restrict__ src, bf16_t* __restrict__ dst, int n8)
{
    int tid = blockIdx.x * 256 + threadIdx.x;
    if (tid >= n8) return;
    float4 a = ((const float4*)src)[tid * 2];
    float4 b = ((const float4*)src)[tid * 2 + 1];
    uint4 o;
    o.x = pk2(a.x, a.y); o.y = pk2(a.z, a.w);
    o.z = pk2(b.x, b.y); o.w = pk2(b.z, b.w);
    ((uint4*)dst)[tid] = o;
}

// Wt[n*Kd + k] = (bf16) W[k*ld + coloff + n]   (transpose + convert)
__global__ __launch_bounds__(256) void tcvt_k(
    const float* __restrict__ W, bf16_t* __restrict__ Wt,
    int Kd, int N, int ld, int coloff)
{
    int tid = blockIdx.x * 256 + threadIdx.x;
    if (tid >= Kd * N) return;
    int k = tid % Kd, n = tid / Kd;
    Wt[tid] = f2bf(W[(size_t)k * ld + coloff + n]);
}

// qkv_wT[j*192 + k] = qkv_w[k*576 + j], j < 288  (one-shot, fixes the
// stride-576 gather in fold_wna_t_k)
__global__ __launch_bounds__(256) void tpose_qkvw_k(
    const float* __restrict__ W, float* __restrict__ WT)
{
    int tid = blockIdx.x * 256 + threadIdx.x;
    if (tid >= 288 * 192) return;
    int k = tid % 192, j = tid / 192;
    WT[tid] = W[(size_t)k * 576 + j];
}

// Wna_t[n*192 + k] = (bf16) sum_j qkv_wT[j,k] * na_qkv_w[j,n], j<288
// (qkv_wT coalesced across k; na_qkv_w broadcast across wave)
__global__ __launch_bounds__(256) void fold_wna_t_k(
    const float* __restrict__ qkv_wT, const float* __restrict__ na_qkv_w,
    bf16_t* __restrict__ Wna_t)
{
    int tid = blockIdx.x * 256 + threadIdx.x;
    if (tid >= 576 * 192) return;
    int k = tid % 192, n = tid / 192;
    float acc = 0.f;
    for (int j = 0; j < 288; j++)
        acc += qkv_wT[j * 192 + k] * na_qkv_w[j * 576 + n];
    Wna_t[tid] = f2bf(acc);
}

__global__ __launch_bounds__(256) void fold_bna_k(
    const float* __restrict__ qkv_b, const float* __restrict__ na_qkv_w,
    const float* __restrict__ na_qkv_b, float* __restrict__ bna)
{
    int j = blockIdx.x * 256 + threadIdx.x;
    if (j >= 576) return;
    float acc = na_qkv_b[j];
    for (int k = 0; k < 288; k++)
        acc += qkv_b[k] * na_qkv_w[k * 576 + j];
    bna[j] = acc;
}

// bt[t,h] = (relu(table(225,2) @ w1 + b1) @ w2)[t,h]
__global__ __launch_bounds__(256) void cpb_k(
    const float* __restrict__ table, const float* __restrict__ w1,
    const float* __restrict__ b1, const float* __restrict__ w2,
    float* __restrict__ bt)
{
    int tid = blockIdx.x * 256 + threadIdx.x;
    if (tid >= 225 * 6) return;
    int h = tid % 6, t = tid / 6;
    float t0 = table[t * 2], t1 = table[t * 2 + 1];
    float acc = 0.f;
    for (int m = 0; m < 512; m++) {
        float hv = t0 * w1[m] + t1 * w1[512 + m] + b1[m];
        hv = fmaxf(hv, 0.f);
        acc += hv * w2[m * 6 + h];
    }
    bt[tid] = acc;
}

// legacy fp32 tiled GEMM (kept for the small anchor-pointwise GEMM)
#define BM 64
#define BN 64
#define BKK 16
template <typename TA, typename TO>
__global__ __launch_bounds__(256) void gemm_k(
    const TA* __restrict__ A, const float* __restrict__ B,
    const float* __restrict__ bias, TO* __restrict__ C,
    int M, int N, int Kd, int lda, int ldb, int ldc)
{
    __shared__ float As[BKK][BM + 1];
    __shared__ float Bs[BKK][BN + 1];
    const int t  = threadIdx.x;
    const int tx = t & 15, ty = t >> 4;
    const int m0 = blockIdx.y * BM, n0 = blockIdx.x * BN;
    float acc[4][4] = {};

    for (int k0 = 0; k0 < Kd; k0 += BKK) {
#pragma unroll
        for (int i = 0; i < 4; i++) {
            int m = (t >> 4) + i * 16;
            int k = t & 15;
            int gm = m0 + m, gk = k0 + k;
            As[k][m] = (gm < M && gk < Kd) ? cvt(A[(size_t)gm * lda + gk]) : 0.f;
        }
#pragma unroll
        for (int i = 0; i < 4; i++) {
            int k = (t >> 6) + i * 4;
            int n = t & 63;
            int gk = k0 + k, gn = n0 + n;
            Bs[k][n] = (gk < Kd && gn < N) ? B[(size_t)gk * ldb + gn] : 0.f;
        }
        __syncthreads();
#pragma unroll
        for (int k = 0; k < BKK; k++) {
            float a[4], b[4];
#pragma unroll
            for (int i = 0; i < 4; i++) a[i] = As[k][ty * 4 + i];
#pragma unroll
            for (int j = 0; j < 4; j++) b[j] = Bs[k][tx * 4 + j];
#pragma unroll
            for (int i = 0; i < 4; i++)
#pragma unroll
                for (int j = 0; j < 4; j++) acc[i][j] += a[i] * b[j];
        }
        __syncthreads();
    }
#pragma unroll
    for (int i = 0; i < 4; i++) {
        int gm = m0 + ty * 4 + i;
        if (gm >= M) continue;
#pragma unroll
        for (int j = 0; j < 4; j++) {
            int gn = n0 + tx * 4 + j;
            if (gn >= N) continue;
            sto(&C[(size_t)gm * ldc + gn], acc[i][j] + bias[gn]);
        }
    }
}

// Depthwise 3x3 stride-2 pad-1 on x (256,256,192) -> adw (128,128,192) fp32
// 4 channels per thread, float4.
__global__ __launch_bounds__(256) void dwconv_k(
    const float* __restrict__ x, const float* __restrict__ w,
    const float* __restrict__ b, float* __restrict__ adw)
{
    int tid = blockIdx.x * 256 + threadIdx.x;
    if (tid >= 16384 * 48) return;
    int c4 = tid % 48;
    int p = tid / 48;
    int ow = p & 127, oh = p >> 7;
    int c = c4 * 4;
    float4 s = *(const float4*)(b + c);
#pragma unroll
    for (int kh = 0; kh < 3; kh++) {
        int ih = oh * 2 - 1 + kh;
        if (ih < 0 || ih >= 256) continue;
#pragma unroll
        for (int kw = 0; kw < 3; kw++) {
            int iw = ow * 2 - 1 + kw;
            if (iw < 0 || iw >= 256) continue;
            float4 xv = *(const float4*)(x + (size_t)(ih * 256 + iw) * 192 + c);
            float4 wv = *(const float4*)(w + (kh * 3 + kw) * 192 + c);
            s.x += xv.x * wv.x; s.y += xv.y * wv.y;
            s.z += xv.z * wv.z; s.w += xv.w * wv.w;
        }
    }
    *(float4*)(adw + (size_t)p * 192 + c) = s;
}

// ---------------------------------------------------------------------------
// Neighborhood attention v6: MFMA. One wave = one 16-query strip in a parity
// plane row. Key window of strip = rows si..si+6, cols c0..c0+31 (c0 8-px
// aligned, covers every query's 7 cols; extras masked, addresses clamped so
// garbage stays finite). Per window row rr:
//   S tiles (2x mfma 16x16x32): A = Q frag (global, lane: q=l&15, d=(l>>4)*8+i)
//     B = K frag (global, col slot 2*(l&15)+t2 -> interleaved cols)
//   flat softmax: e = exp(s*scale + rpb[(rbh0+rr)*13 + c-pj+6]), masked -> 0
//   P: v_cvt_pk_bf16_f32 pairs (slots 2lm,2lm+1) -> per-wave LDS [16][32+pad]
//   PV (2x mfma): A = P frag (LDS, 16B contiguous), B = V gathered shorts
// Out D-layout row=q matches sums layout; normalize by 1/sum in epilogue.
// block: 256 thr = 4 waves; grid (2, 128, 24).
// ---------------------------------------------------------------------------
__global__ __launch_bounds__(256) void na_attn_k(
    const bf16_t* __restrict__ nap, const float* __restrict__ rpb,
    bf16_t* __restrict__ outp)
{
    __shared__ float rpb_s[176];
    __shared__ __align__(16) unsigned P_s[4][16][20];   // [wave][q][slot-pair], 80B rows

    const int t = threadIdx.x;
    const int wv = t >> 6, lane = t & 63;
    const int lm = lane & 15, lq = lane >> 4;
    const int z = blockIdx.z;
    const int h = z >> 2, par = z & 3;

    if (t < 169) rpb_s[t] = rpb[h * 169 + t];
    __syncthreads();

    const int pi  = blockIdx.y;
    const int pj0 = blockIdx.x * 64 + wv * 16;
    const int si  = min(max(pi - 3, 0), 121);
    const int rbh0 = si - pi + 6;
    const int c0  = min(max(pj0 - 3, 0), 121) & ~7;

    const size_t plane = (size_t)65536 * 32;
    const size_t poff  = (size_t)(par * 16384) * 32;
    const bf16_t* qpl = nap + (size_t)h * plane + poff;
    const bf16_t* kpl = nap + (size_t)(6 + h) * plane + poff;
    const bf16_t* vpl = nap + (size_t)(12 + h) * plane + poff;

    // Q A-frag: row = lm (query), dims lq*8..lq*8+7  (16B from global)
    const short8 qf = *(const short8*)(qpl + ((size_t)(pi * 128 + pj0 + lm)) * 32 + lq * 8);

    // per-strip constants (row-independent)
    int offc[4][2]; bool vm[4][2];
#pragma unroll
    for (int r = 0; r < 4; r++) {
        int q = lq * 4 + r, pj = pj0 + q;
        int sj = min(max(pj - 3, 0), 121);
#pragma unroll
        for (int t2 = 0; t2 < 2; t2++) {
            int c = c0 + 2 * lm + t2;
            vm[r][t2] = (c >= sj) && (c <= sj + 6);
            offc[r][t2] = min(max(c - pj + 6, 0), 12);
        }
    }
    const int kc0 = min(c0 + 2 * lm,     127) * 64;   // byte offsets (64B/px)
    const int kc1 = min(c0 + 2 * lm + 1, 127) * 64;
    int vcoff[8];
#pragma unroll
    for (int i = 0; i < 8; i++) vcoff[i] = min(c0 + lq * 8 + i, 127) * 64;

    const float scale = 0.17677669529663687f; // 32^-0.5
    f32x4 o0 = {}, o1 = {};
    float sums[4] = {0.f, 0.f, 0.f, 0.f};
    const f32x4 zz = {};

#pragma unroll 2
    for (int rr = 0; rr < 7; rr++) {
        const size_t rb2 = (size_t)((si + rr) * 128) * 64;  // row base, bytes
        const char* krow = (const char*)kpl + rb2;
        const char* vrow = (const char*)vpl + rb2;

        short8 kf0 = *(const short8*)(krow + kc0 + lq * 16);
        short8 kf1 = *(const short8*)(krow + kc1 + lq * 16);
        f32x4 s0 = __builtin_amdgcn_mfma_f32_16x16x32_bf16(qf, kf0, zz, 0, 0, 0);
        f32x4 s1 = __builtin_amdgcn_mfma_f32_16x16x32_bf16(qf, kf1, zz, 0, 0, 0);

        const float* br = rpb_s + (rbh0 + rr) * 13;
        float e0[4], e1[4];
#pragma unroll
        for (int r = 0; r < 4; r++) {
            float a0 = __expf(fmaf(s0[r], scale, br[offc[r][0]]));
            float a1 = __expf(fmaf(s1[r], scale, br[offc[r][1]]));
            a0 = vm[r][0] ? a0 : 0.f;
            a1 = vm[r][1] ? a1 : 0.f;
            e0[r] = a0; e1[r] = a1;
            sums[r] += a0 + a1;
        }
#pragma unroll
        for (int r = 0; r < 4; r++) {
            unsigned pr;
            asm("v_cvt_pk_bf16_f32 %0, %1, %2" : "=v"(pr) : "v"(e0[r]), "v"(e1[r]));
            P_s[wv][lq * 4 + r][lm] = pr;   // slots 2lm (lo), 2lm+1 (hi)
        }
        // P A-frag: row = lm (query), slots lq*8..lq*8+7 (16B contiguous)
        const short8 pf = *(const short8*)((const bf16_t*)P_s[wv][lm] + lq * 8);

        short8 vf0, vf1;
        const char* v0b = vrow + lm * 2;
        const char* v1b = vrow + 32 + lm * 2;
#pragma unroll
        for (int i = 0; i < 8; i++) {
            ((bf16_t*)&vf0)[i] = *(const bf16_t*)(v0b + vcoff[i]);
            ((bf16_t*)&vf1)[i] = *(const bf16_t*)(v1b + vcoff[i]);
        }
        o0 = __builtin_amdgcn_mfma_f32_16x16x32_bf16(pf, vf0, o0, 0, 0, 0);
        o1 = __builtin_amdgcn_mfma_f32_16x16x32_bf16(pf, vf1, o1, 0, 0, 0);
    }

#pragma unroll
    for (int r = 0; r < 4; r++) {
        float s = sums[r];
        s += __shfl_xor(s, 1, 64);
        s += __shfl_xor(s, 2, 64);
        s += __shfl_xor(s, 4, 64);
        s += __shfl_xor(s, 8, 64);
        sums[r] = 1.0f / s;
    }

    const int gi = par >> 1, gj = par & 1;
    const int i0 = pi * 2 + gi;
    bf16_t* ob = outp + ((size_t)i0 * 256 + gj) * 192 + h * 32 + lm;
#pragma unroll
    for (int r = 0; r < 4; r++) {
        int q = lq * 4 + r;
        size_t px = (size_t)(pj0 + q) * 2 * 192;
        ob[px]      = f2bf(o0[r] * sums[r]);
        ob[px + 16] = f2bf(o1[r] * sums[r]);
    }
}

// Stripe stage 1 (single pass, FLAT softmax):
// x1[w,h,n2,:] = softmax(cos(an,k_s)*scale + bias) @ v_s
__global__ __launch_bounds__(256) void attn1_k(
    const float* __restrict__ apw,    // (16384,96) fp32
    const bf16_t* __restrict__ qkvs,  // (65536,288) bf16: which*96+h*16+d
    const float* __restrict__ bt1, const int* __restrict__ idx,
    const float* __restrict__ ls1,
    float* __restrict__ x1)           // (1024,6,16,16) fp32
{
    int tid = blockIdx.x * 256 + threadIdx.x;
    if (tid >= 1024 * 6 * 16) return;
    int n2 = tid & 15;
    int h = (tid >> 4) % 6;
    int w = tid / 96;
    int wi = w >> 5, wj = w & 31;
    float scale = __expf(fminf(ls1[h], 4.605170185988091f));

    int ay = wi * 4 + (n2 >> 2), ax = wj * 4 + (n2 & 3);
    const float* ap = apw + (size_t)(ay * 128 + ax) * 96 + h * 16;
    float qv[16]; float nrm = 0.f;
#pragma unroll
    for (int d = 0; d < 16; d += 4) {
        float4 v = *(const float4*)(ap + d);
        qv[d] = v.x; qv[d + 1] = v.y; qv[d + 2] = v.z; qv[d + 3] = v.w;
        nrm += v.x * v.x + v.y * v.y + v.z * v.z + v.w * v.w;
    }
    float innorm = 1.0f / fmaxf(sqrtf(nrm), 1e-12f);
#pragma unroll
    for (int d = 0; d < 16; d++) qv[d] *= innorm;

    float sum = 0.f;
    float acc[16] = {};
#pragma unroll 4
    for (int m = 0; m < 64; m++) {
        int ky = wi * 8 + (m >> 3), kx = wj * 8 + (m & 7);
        const bf16_t* kp = qkvs + (size_t)(ky * 256 + kx) * 288 + 96 + h * 16;
        float kv[16];
        ld_bf8(kp, kv); ld_bf8(kp + 8, kv + 8);
        float dot = 0.f, kn = 0.f;
#pragma unroll
        for (int d = 0; d < 16; d++) { dot += qv[d] * kv[d]; kn += kv[d] * kv[d]; }
        dot *= 1.0f / fmaxf(sqrtf(kn), 1e-12f);
        float bias = 16.0f / (1.0f + __expf(-bt1[idx[n2 * 64 + m] * 6 + h]));
        float e = __expf(dot * scale + bias);
        sum += e;
        const bf16_t* vp = qkvs + (size_t)(ky * 256 + kx) * 288 + 192 + h * 16;
        float vv[16];
        ld_bf8(vp, vv); ld_bf8(vp + 8, vv + 8);
#pragma unroll
        for (int d = 0; d < 16; d++) acc[d] += e * vv[d];
    }
    float inv = 1.0f / sum;
    float* xp = x1 + ((size_t)w * 6 + h) * 256 + n2 * 16;
#pragma unroll
    for (int d = 0; d < 16; d += 4)
        *(float4*)(xp + d) = make_float4(acc[d] * inv, acc[d + 1] * inv,
                                         acc[d + 2] * inv, acc[d + 3] * inv);
}

// Stripe stage 2 -> cat[:, 96:192] (bf16), window-reversed (flat softmax,
// logits[16] fully unrolled -> registers)
__global__ __launch_bounds__(256) void attn2_k(
    const float* __restrict__ apw,
    const bf16_t* __restrict__ qkvs,
    const float* __restrict__ bt2, const int* __restrict__ idx,
    const float* __restrict__ ls2,
    const float* __restrict__ x1,
    bf16_t* __restrict__ cat)         // (65536,192) bf16, cols 96..191
{
    int tid = blockIdx.x * 256 + threadIdx.x;
    if (tid >= 1024 * 6 * 64) return;
    int n1 = tid & 63;
    int h = (tid >> 6) % 6;
    int w = tid / 384;
    int wi = w >> 5, wj = w & 31;
    float scale = __expf(fminf(ls2[h], 4.605170185988091f));

    int qy = wi * 8 + (n1 >> 3), qx = wj * 8 + (n1 & 7);
    const bf16_t* qp = qkvs + (size_t)(qy * 256 + qx) * 288 + h * 16;
    float qv[16];
    ld_bf8(qp, qv); ld_bf8(qp + 8, qv + 8);
    float nrm = 0.f;
#pragma unroll
    for (int d = 0; d < 16; d++) nrm += qv[d] * qv[d];
    float innorm = 1.0f / fmaxf(sqrtf(nrm), 1e-12f);
#pragma unroll
    for (int d = 0; d < 16; d++) qv[d] *= innorm;

    float sum = 0.f;
    float acc[16] = {};
#pragma unroll
    for (int m = 0; m < 16; m++) {
        int ay = wi * 4 + (m >> 2), ax = wj * 4 + (m & 3);
        const float* ap = apw + (size_t)(ay * 128 + ax) * 96 + h * 16;
        float dot = 0.f, kn = 0.f;
#pragma unroll
        for (int d = 0; d < 16; d += 4) {
            float4 v = *(const float4*)(ap + d);
            dot += qv[d] * v.x + qv[d + 1] * v.y + qv[d + 2] * v.z + qv[d + 3] * v.w;
            kn += v.x * v.x + v.y * v.y + v.z * v.z + v.w * v.w;
        }
        dot *= 1.0f / fmaxf(sqrtf(kn), 1e-12f);
        float bias = 16.0f / (1.0f + __expf(-bt2[idx[n1 * 16 + m] * 6 + h]));
        float e = __expf(dot * scale + bias);
        sum += e;
        const float* vp = x1 + ((size_t)w * 6 + h) * 256 + m * 16;
#pragma unroll
        for (int d = 0; d < 16; d += 4) {
            float4 v = *(const float4*)(vp + d);
            acc[d] += e * v.x; acc[d + 1] += e * v.y;
            acc[d + 2] += e * v.z; acc[d + 3] += e * v.w;
        }
    }
    float inv = 1.0f / sum;
#pragma unroll
    for (int d = 0; d < 16; d++) acc[d] *= inv;
    bf16_t* op = cat + (size_t)(qy * 256 + qx) * 192 + 96 + h * 16;
    uint4 o0, o1;
    o0.x = pk2(acc[0], acc[1]);   o0.y = pk2(acc[2], acc[3]);
    o0.z = pk2(acc[4], acc[5]);   o0.w = pk2(acc[6], acc[7]);
    o1.x = pk2(acc[8], acc[9]);   o1.y = pk2(acc[10], acc[11]);
    o1.z = pk2(acc[12], acc[13]); o1.w = pk2(acc[14], acc[15]);
    *(uint4*)(op) = o0;
    *(uint4*)(op + 8) = o1;
}

extern "C" void kernel_launch(void* const* d_in, const int* in_sizes, int n_in,
                              void* d_out, int out_size, void* d_ws, size_t ws_size,
                              hipStream_t stream) {
    const float* x          = (const float*)d_in[0];
    const float* table      = (const float*)d_in[3];
    const int*   idx_a2w    = (const int*)d_in[4];
    const int*   idx_w2a    = (const int*)d_in[5];
    const float* qkv_w      = (const float*)d_in[6];
    const float* qkv_b      = (const float*)d_in[7];
    const float* adw_w      = (const float*)d_in[8];
    const float* adw_b      = (const float*)d_in[9];
    const float* apw_w      = (const float*)d_in[10];
    const float* apw_b      = (const float*)d_in[11];
    const float* na_qkv_w   = (const float*)d_in[12];
    const float* na_qkv_b   = (const float*)d_in[13];
    const float* na_after_w = (const float*)d_in[14];
    const float* na_after_b = (const float*)d_in[15];
    const float* na_rpb     = (const float*)d_in[16];
    const float* ls1        = (const float*)d_in[17];
    const float* cpb1_w1    = (const float*)d_in[18];
    const float* cpb1_b1    = (const float*)d_in[19];
    const float* cpb1_w2    = (const float*)d_in[20];
    const float* ls2        = (const float*)d_in[21];
    const float* cpb2_w1    = (const float*)d_in[22];
    const float* cpb2_b1    = (const float*)d_in[23];
    const float* cpb2_w2    = (const float*)d_in[24];
    const float* proj_w     = (const float*)d_in[25];
    const float* proj_b     = (const float*)d_in[26];
    float* out = (float*)d_out;
    (void)in_sizes; (void)n_in; (void)out_size; (void)ws_size;

    // ---- byte-based workspace allocator (256B aligned) ----
    char* base = (char*)d_ws;
    size_t off = 0;
    auto alloc = [&](size_t bytes) {
        off = (off + 255) & ~(size_t)255;
        void* p = base + off; off += bytes; return p;
    };
    float*  bna    = (float*)alloc(576 * 4);
    float*  bt1    = (float*)alloc(225 * 6 * 4);
    float*  bt2    = (float*)alloc(225 * 6 * 4);
    float*  qkv_wT = (float*)alloc(288 * 192 * 4);
    bf16_t* Wna_t  = (bf16_t*)alloc(576 * 192 * 2);
    bf16_t* Ws_t   = (bf16_t*)alloc(288 * 192 * 2);
    bf16_t* Waft_t = (bf16_t*)alloc(96 * 192 * 2);
    bf16_t* Wproj_t= (bf16_t*)alloc(192 * 192 * 2);
    bf16_t* qkvs   = (bf16_t*)alloc((size_t)65536 * 288 * 2);  // 37.75 MB
    char*   naR    = (char*)alloc((size_t)65536 * 576 * 2);    // 75.5 MB region
    char*   R      = (char*)alloc((size_t)65536 * 192 * 2);    // 25.2 MB region
    float*  apw    = (float*)alloc((size_t)16384 * 96 * 4);    // 6.3 MB
    // region aliases (strictly sequential lifetimes on the in-order stream):
    bf16_t* naqkv   = (bf16_t*)naR;               // naqkv gemm .. na_attn (planes)
    float*  x1      = (float*)naR;                // attn1 .. attn2 (6.3 MB)
    bf16_t* cat     = (bf16_t*)(naR + (8 << 20)); // na_after .. proj (25.2 MB)
    bf16_t* xb      = (bf16_t*)R;                 // cvt .. naqkv gemm (25.2 MB)
    float*  adw     = (float*)R;                  // dwconv .. apw gemm (12.6 MB)
    bf16_t* xna_pre = (bf16_t*)R;                 // na_attn .. na_after (25.2 MB)
    // peak ~= 0.8 + 37.75 + 75.5 + 25.2 + 6.3 ~= 145.6 MB

    // Tiny precomputes (independent)
    tpose_qkvw_k<<<216, 256, 0, stream>>>(qkv_w, qkv_wT);
    fold_wna_t_k<<<432, 256, 0, stream>>>(qkv_wT, na_qkv_w, Wna_t);
    fold_bna_k<<<3, 256, 0, stream>>>(qkv_b, na_qkv_w, na_qkv_b, bna);
    cpb_k<<<6, 256, 0, stream>>>(table, cpb1_w1, cpb1_b1, cpb1_w2, bt1);
    cpb_k<<<6, 256, 0, stream>>>(table, cpb2_w1, cpb2_b1, cpb2_w2, bt2);
    tcvt_k<<<216, 256, 0, stream>>>(qkv_w, Ws_t, 192, 288, 576, 288);
    tcvt_k<<<72, 256, 0, stream>>>(na_after_w, Waft_t, 192, 96, 96, 0);
    tcvt_k<<<144, 256, 0, stream>>>(proj_w, Wproj_t, 192, 192, 192, 0);
    cvt_bf16_k<<<6144, 256, 0, stream>>>(x, xb, 65536 * 192 / 8);

    // Stripe qkv: xb @ Ws_t^T + b -> qkvs bf16 (65536,288), row-major
    mfma_gemm_k<192, 0, bf16_t><<<dim3(3, 512), 256, 0, stream>>>(
        xb, Ws_t, qkv_b + 288, qkvs, 192, 192, 288);

    // Folded NA qkv: xb @ Wna_t^T + bna -> naqkv bf16 parity-split planes
    mfma_gemm_k<192, 1, bf16_t><<<dim3(6, 512), 256, 0, stream>>>(
        xb, Wna_t, bna, naqkv, 192, 192, 576);

    // Anchor: depthwise conv (xb dead -> adw in R), pointwise GEMM -> apw
    dwconv_k<<<3072, 256, 0, stream>>>(x, adw_w, adw_b, adw);
    gemm_k<float, float><<<dim3(2, 256), 256, 0, stream>>>(
        adw, apw_w, apw_b, apw, 16384, 96, 192, 192, 96, 96);

    // Neighborhood attention (adw dead -> xna_pre in R)
    na_attn_k<<<dim3(2, 128, 24), 256, 0, stream>>>(naqkv, na_rpb, xna_pre);

    // na_after: xna_pre @ Waft_t^T + b -> cat[:,0:96]  (naqkv dead)
    mfma_gemm_k<192, 0, bf16_t><<<dim3(1, 512), 256, 0, stream>>>(
        xna_pre, Waft_t, na_after_b, cat, 192, 192, 192);

    // Stripe attention -> x1, then cat[:,96:192]
    attn1_k<<<384, 256, 0, stream>>>(apw, qkvs, bt1, idx_a2w, ls1, x1);
    attn2_k<<<1536, 256, 0, stream>>>(apw, qkvs, bt2, idx_w2a, ls2, x1, cat);

    // Final projection: cat @ Wproj_t^T + proj_b -> out fp32
    mfma_gemm_k<192, 0, float><<<dim3(2, 512), 256, 0, stream>>>(
        cat, Wproj_t, proj_b, out, 192, 192, 192);
}

// Round 2
// 666.502 us; speedup vs baseline: 1.0837x; 1.0088x over previous
//
#include <hip/hip_runtime.h>
#include <math.h>

// ---------------------------------------------------------------------------
// MixedAttention: H=W=256, C=192, HEADS=6, NA: K=7 DIL=2 hd=32,
// stripe: WS=8 AWS=4 hs=16, 1024 windows.
// R9: attn1 latency fix. attn1 was 85us @ Occupancy 14% / VALUBusy 25%
// (384 blocks, 64-iter serial loop with idx->bt->exp dependent chain).
// Now: 8 sub-lanes per output (one window-row of keys each, shfl_xor
// reduce), grid 384->3072 blocks; and bias matrices precomputed once
// (sigb_k) so both attn inner loops lose the gather+sigmoid chain.
// ---------------------------------------------------------------------------

typedef unsigned short bf16_t;
typedef __attribute__((ext_vector_type(8))) short short8;   // MFMA A/B frag (8 bf16)
typedef __attribute__((ext_vector_type(4))) float f32x4;    // MFMA C/D frag

__device__ inline float bf2f(bf16_t v) { return __uint_as_float((unsigned)v << 16); }
__device__ inline bf16_t f2bf(float f) {
    unsigned u = __float_as_uint(f);
    unsigned r = (u + 0x7fffu + ((u >> 16) & 1u)) >> 16;   // RNE, finite inputs
    return (bf16_t)r;
}
__device__ inline float cvt(float v) { return v; }
__device__ inline float cvt(bf16_t v) { return bf2f(v); }
__device__ inline void sto(float* p, float v) { *p = v; }
__device__ inline void sto(bf16_t* p, float v) { *p = f2bf(v); }

// load 8 consecutive bf16 (16B aligned) -> 8 floats
__device__ inline void ld_bf8(const bf16_t* p, float* d) {
    uint4 r = *(const uint4*)p;
    d[0] = __uint_as_float(r.x << 16); d[1] = __uint_as_float(r.x & 0xffff0000u);
    d[2] = __uint_as_float(r.y << 16); d[3] = __uint_as_float(r.y & 0xffff0000u);
    d[4] = __uint_as_float(r.z << 16); d[5] = __uint_as_float(r.z & 0xffff0000u);
    d[6] = __uint_as_float(r.w << 16); d[7] = __uint_as_float(r.w & 0xffff0000u);
}
__device__ inline unsigned pk2(float a, float b) {
    return (unsigned)f2bf(a) | ((unsigned)f2bf(b) << 16);
}

// ---------------------------------------------------------------------------
// MFMA GEMM: C[M,N] = A[M,K]bf16 @ Bt[N,K]^T + bias. Tile 128x96, 4 waves,
// each wave 64x48 = 4x3 16x16 frags, K=192 fully unrolled, no LDS.
// NA=1: scatter-store into parity-split head planes:
//   ((which*6+h)*65536 + par*16384 + pi*128 + pj)*32 + d
// ---------------------------------------------------------------------------
template <int KD, int NA, typename TO>
__global__ __launch_bounds__(256) void mfma_gemm_k(
    const bf16_t* __restrict__ A, const bf16_t* __restrict__ Bt,
    const float* __restrict__ bias, TO* __restrict__ C,
    int lda, int ldb, int ldc)
{
    const int t = threadIdx.x;
    const int lane = t & 63, wave = t >> 6;
    const int wr = wave >> 1, wc = wave & 1;
    const int m0 = blockIdx.y * 128 + wr * 64;
    const int n0 = blockIdx.x * 96 + wc * 48;
    const int lm = lane & 15;
    const int q  = lane >> 4;

    f32x4 acc[4][3] = {};
    const bf16_t* ap = A + (size_t)(m0 + lm) * lda + q * 8;
    const bf16_t* bp = Bt + (size_t)(n0 + lm) * ldb + q * 8;

#pragma unroll
    for (int k0 = 0; k0 < KD; k0 += 32) {
        short8 af[4], bf[3];
#pragma unroll
        for (int mi = 0; mi < 4; mi++)
            af[mi] = *(const short8*)(ap + (size_t)(mi * 16) * lda + k0);
#pragma unroll
        for (int ni = 0; ni < 3; ni++)
            bf[ni] = *(const short8*)(bp + (size_t)(ni * 16) * ldb + k0);
#pragma unroll
        for (int mi = 0; mi < 4; mi++)
#pragma unroll
            for (int ni = 0; ni < 3; ni++)
                acc[mi][ni] = __builtin_amdgcn_mfma_f32_16x16x32_bf16(
                    af[mi], bf[ni], acc[mi][ni], 0, 0, 0);
    }

#pragma unroll
    for (int mi = 0; mi < 4; mi++) {
#pragma unroll
        for (int ni = 0; ni < 3; ni++) {
            int col = n0 + ni * 16 + lm;
            float bv = bias[col];
            if (NA) {
                int which = col / 192;
                int hh = (col % 192) / 32;
                int d  = col % 32;
                size_t pbase = ((size_t)which * 6 + hh) * ((size_t)65536 * 32) + d;
#pragma unroll
                for (int r = 0; r < 4; r++) {
                    int row = m0 + mi * 16 + q * 4 + r;
                    int ii = row >> 8, jj = row & 255;
                    int par = ((ii & 1) << 1) | (jj & 1);
                    int pix = par * 16384 + (ii >> 1) * 128 + (jj >> 1);
                    sto(&C[pbase + (size_t)pix * 32], acc[mi][ni][r] + bv);
                }
            } else {
#pragma unroll
                for (int r = 0; r < 4; r++) {
                    int row = m0 + mi * 16 + q * 4 + r;
                    sto(&C[(size_t)row * ldc + col], acc[mi][ni][r] + bv);
                }
            }
        }
    }
}

// x fp32 -> bf16, 8 elems/thread
__global__ __launch_bounds__(256) void cvt_bf16_k(
    const float* __restrict__ src, bf16_t* __restrict__ dst, int n8)
{
    int tid = blockIdx.x * 256 + threadIdx.x;
    if (tid >= n8) return;
    float4 a = ((const float4*)src)[tid * 2];
    float4 b = ((const float4*)src)[tid * 2 + 1];
    uint4 o;
    o.x = pk2(a.x, a.y); o.y = pk2(a.z, a.w);
    o.z = pk2(b.x, b.y); o.w = pk2(b.z, b.w);
    ((uint4*)dst)[tid] = o;
}

// Wt[n*Kd + k] = (bf16) W[k*ld + coloff + n]   (transpose + convert)
__global__ __launch_bounds__(256) void tcvt_k(
    const float* __restrict__ W, bf16_t* __restrict__ Wt,
    int Kd, int N, int ld, int coloff)
{
    int tid = blockIdx.x * 256 + threadIdx.x;
    if (tid >= Kd * N) return;
    int k = tid % Kd, n = tid / Kd;
    Wt[tid] = f2bf(W[(size_t)k * ld + coloff + n]);
}

// qkv_wT[j*192 + k] = qkv_w[k*576 + j], j < 288  (one-shot, fixes the
// stride-576 gather in fold_wna_t_k)
__global__ __launch_bounds__(256) void tpose_qkvw_k(
    const float* __restrict__ W, float* __restrict__ WT)
{
    int tid = blockIdx.x * 256 + threadIdx.x;
    if (tid >= 288 * 192) return;
    int k = tid % 192, j = tid / 192;
    WT[tid] = W[(size_t)k * 576 + j];
}

// Wna_t[n*192 + k] = (bf16) sum_j qkv_wT[j,k] * na_qkv_w[j,n], j<288
__global__ __launch_bounds__(256) void fold_wna_t_k(
    const float* __restrict__ qkv_wT, const float* __restrict__ na_qkv_w,
    bf16_t* __restrict__ Wna_t)
{
    int tid = blockIdx.x * 256 + threadIdx.x;
    if (tid >= 576 * 192) return;
    int k = tid % 192, n = tid / 192;
    float acc = 0.f;
    for (int j = 0; j < 288; j++)
        acc += qkv_wT[j * 192 + k] * na_qkv_w[j * 576 + n];
    Wna_t[tid] = f2bf(acc);
}

__global__ __launch_bounds__(256) void fold_bna_k(
    const float* __restrict__ qkv_b, const float* __restrict__ na_qkv_w,
    const float* __restrict__ na_qkv_b, float* __restrict__ bna)
{
    int j = blockIdx.x * 256 + threadIdx.x;
    if (j >= 576) return;
    float acc = na_qkv_b[j];
    for (int k = 0; k < 288; k++)
        acc += qkv_b[k] * na_qkv_w[k * 576 + j];
    bna[j] = acc;
}

// bt[t,h] = (relu(table(225,2) @ w1 + b1) @ w2)[t,h]
__global__ __launch_bounds__(256) void cpb_k(
    const float* __restrict__ table, const float* __restrict__ w1,
    const float* __restrict__ b1, const float* __restrict__ w2,
    float* __restrict__ bt)
{
    int tid = blockIdx.x * 256 + threadIdx.x;
    if (tid >= 225 * 6) return;
    int h = tid % 6, t = tid / 6;
    float t0 = table[t * 2], t1 = table[t * 2 + 1];
    float acc = 0.f;
    for (int m = 0; m < 512; m++) {
        float hv = t0 * w1[m] + t1 * w1[512 + m] + b1[m];
        hv = fmaxf(hv, 0.f);
        acc += hv * w2[m * 6 + h];
    }
    bt[tid] = acc;
}

// bp[h*1024 + p] = 16*sigmoid(bt[idx[p]*6 + h]) — hoists the idx->bt->exp
// dependent chain out of the attention inner loops.
__global__ __launch_bounds__(256) void sigb_k(
    const float* __restrict__ bt, const int* __restrict__ idx,
    float* __restrict__ bp)
{
    int tid = blockIdx.x * 256 + threadIdx.x;
    if (tid >= 6144) return;
    int h = tid >> 10, p = tid & 1023;
    bp[tid] = 16.0f / (1.0f + __expf(-bt[idx[p] * 6 + h]));
}

// legacy fp32 tiled GEMM (kept for the small anchor-pointwise GEMM)
#define BM 64
#define BN 64
#define BKK 16
template <typename TA, typename TO>
__global__ __launch_bounds__(256) void gemm_k(
    const TA* __restrict__ A, const float* __restrict__ B,
    const float* __restrict__ bias, TO* __restrict__ C,
    int M, int N, int Kd, int lda, int ldb, int ldc)
{
    __shared__ float As[BKK][BM + 1];
    __shared__ float Bs[BKK][BN + 1];
    const int t  = threadIdx.x;
    const int tx = t & 15, ty = t >> 4;
    const int m0 = blockIdx.y * BM, n0 = blockIdx.x * BN;
    float acc[4][4] = {};

    for (int k0 = 0; k0 < Kd; k0 += BKK) {
#pragma unroll
        for (int i = 0; i < 4; i++) {
            int m = (t >> 4) + i * 16;
            int k = t & 15;
            int gm = m0 + m, gk = k0 + k;
            As[k][m] = (gm < M && gk < Kd) ? cvt(A[(size_t)gm * lda + gk]) : 0.f;
        }
#pragma unroll
        for (int i = 0; i < 4; i++) {
            int k = (t >> 6) + i * 4;
            int n = t & 63;
            int gk = k0 + k, gn = n0 + n;
            Bs[k][n] = (gk < Kd && gn < N) ? B[(size_t)gk * ldb + gn] : 0.f;
        }
        __syncthreads();
#pragma unroll
        for (int k = 0; k < BKK; k++) {
            float a[4], b[4];
#pragma unroll
            for (int i = 0; i < 4; i++) a[i] = As[k][ty * 4 + i];
#pragma unroll
            for (int j = 0; j < 4; j++) b[j] = Bs[k][tx * 4 + j];
#pragma unroll
            for (int i = 0; i < 4; i++)
#pragma unroll
                for (int j = 0; j < 4; j++) acc[i][j] += a[i] * b[j];
        }
        __syncthreads();
    }
#pragma unroll
    for (int i = 0; i < 4; i++) {
        int gm = m0 + ty * 4 + i;
        if (gm >= M) continue;
#pragma unroll
        for (int j = 0; j < 4; j++) {
            int gn = n0 + tx * 4 + j;
            if (gn >= N) continue;
            sto(&C[(size_t)gm * ldc + gn], acc[i][j] + bias[gn]);
        }
    }
}

// Depthwise 3x3 stride-2 pad-1 on x (256,256,192) -> adw (128,128,192) fp32
__global__ __launch_bounds__(256) void dwconv_k(
    const float* __restrict__ x, const float* __restrict__ w,
    const float* __restrict__ b, float* __restrict__ adw)
{
    int tid = blockIdx.x * 256 + threadIdx.x;
    if (tid >= 16384 * 48) return;
    int c4 = tid % 48;
    int p = tid / 48;
    int ow = p & 127, oh = p >> 7;
    int c = c4 * 4;
    float4 s = *(const float4*)(b + c);
#pragma unroll
    for (int kh = 0; kh < 3; kh++) {
        int ih = oh * 2 - 1 + kh;
        if (ih < 0 || ih >= 256) continue;
#pragma unroll
        for (int kw = 0; kw < 3; kw++) {
            int iw = ow * 2 - 1 + kw;
            if (iw < 0 || iw >= 256) continue;
            float4 xv = *(const float4*)(x + (size_t)(ih * 256 + iw) * 192 + c);
            float4 wv = *(const float4*)(w + (kh * 3 + kw) * 192 + c);
            s.x += xv.x * wv.x; s.y += xv.y * wv.y;
            s.z += xv.z * wv.z; s.w += xv.w * wv.w;
        }
    }
    *(float4*)(adw + (size_t)p * 192 + c) = s;
}

// ---------------------------------------------------------------------------
// Neighborhood attention v6: MFMA (unchanged from R8, verified).
// ---------------------------------------------------------------------------
__global__ __launch_bounds__(256) void na_attn_k(
    const bf16_t* __restrict__ nap, const float* __restrict__ rpb,
    bf16_t* __restrict__ outp)
{
    __shared__ float rpb_s[176];
    __shared__ __align__(16) unsigned P_s[4][16][20];   // [wave][q][slot-pair]

    const int t = threadIdx.x;
    const int wv = t >> 6, lane = t & 63;
    const int lm = lane & 15, lq = lane >> 4;
    const int z = blockIdx.z;
    const int h = z >> 2, par = z & 3;

    if (t < 169) rpb_s[t] = rpb[h * 169 + t];
    __syncthreads();

    const int pi  = blockIdx.y;
    const int pj0 = blockIdx.x * 64 + wv * 16;
    const int si  = min(max(pi - 3, 0), 121);
    const int rbh0 = si - pi + 6;
    const int c0  = min(max(pj0 - 3, 0), 121) & ~7;

    const size_t plane = (size_t)65536 * 32;
    const size_t poff  = (size_t)(par * 16384) * 32;
    const bf16_t* qpl = nap + (size_t)h * plane + poff;
    const bf16_t* kpl = nap + (size_t)(6 + h) * plane + poff;
    const bf16_t* vpl = nap + (size_t)(12 + h) * plane + poff;

    const short8 qf = *(const short8*)(qpl + ((size_t)(pi * 128 + pj0 + lm)) * 32 + lq * 8);

    int offc[4][2]; bool vm[4][2];
#pragma unroll
    for (int r = 0; r < 4; r++) {
        int q = lq * 4 + r, pj = pj0 + q;
        int sj = min(max(pj - 3, 0), 121);
#pragma unroll
        for (int t2 = 0; t2 < 2; t2++) {
            int c = c0 + 2 * lm + t2;
            vm[r][t2] = (c >= sj) && (c <= sj + 6);
            offc[r][t2] = min(max(c - pj + 6, 0), 12);
        }
    }
    const int kc0 = min(c0 + 2 * lm,     127) * 64;   // byte offsets (64B/px)
    const int kc1 = min(c0 + 2 * lm + 1, 127) * 64;
    int vcoff[8];
#pragma unroll
    for (int i = 0; i < 8; i++) vcoff[i] = min(c0 + lq * 8 + i, 127) * 64;

    const float scale = 0.17677669529663687f; // 32^-0.5
    f32x4 o0 = {}, o1 = {};
    float sums[4] = {0.f, 0.f, 0.f, 0.f};
    const f32x4 zz = {};

#pragma unroll 2
    for (int rr = 0; rr < 7; rr++) {
        const size_t rb2 = (size_t)((si + rr) * 128) * 64;  // row base, bytes
        const char* krow = (const char*)kpl + rb2;
        const char* vrow = (const char*)vpl + rb2;

        short8 kf0 = *(const short8*)(krow + kc0 + lq * 16);
        short8 kf1 = *(const short8*)(krow + kc1 + lq * 16);
        f32x4 s0 = __builtin_amdgcn_mfma_f32_16x16x32_bf16(qf, kf0, zz, 0, 0, 0);
        f32x4 s1 = __builtin_amdgcn_mfma_f32_16x16x32_bf16(qf, kf1, zz, 0, 0, 0);

        const float* br = rpb_s + (rbh0 + rr) * 13;
        float e0[4], e1[4];
#pragma unroll
        for (int r = 0; r < 4; r++) {
            float a0 = __expf(fmaf(s0[r], scale, br[offc[r][0]]));
            float a1 = __expf(fmaf(s1[r], scale, br[offc[r][1]]));
            a0 = vm[r][0] ? a0 : 0.f;
            a1 = vm[r][1] ? a1 : 0.f;
            e0[r] = a0; e1[r] = a1;
            sums[r] += a0 + a1;
        }
#pragma unroll
        for (int r = 0; r < 4; r++) {
            unsigned pr;
            asm("v_cvt_pk_bf16_f32 %0, %1, %2" : "=v"(pr) : "v"(e0[r]), "v"(e1[r]));
            P_s[wv][lq * 4 + r][lm] = pr;   // slots 2lm (lo), 2lm+1 (hi)
        }
        const short8 pf = *(const short8*)((const bf16_t*)P_s[wv][lm] + lq * 8);

        short8 vf0, vf1;
        const char* v0b = vrow + lm * 2;
        const char* v1b = vrow + 32 + lm * 2;
#pragma unroll
        for (int i = 0; i < 8; i++) {
            ((bf16_t*)&vf0)[i] = *(const bf16_t*)(v0b + vcoff[i]);
            ((bf16_t*)&vf1)[i] = *(const bf16_t*)(v1b + vcoff[i]);
        }
        o0 = __builtin_amdgcn_mfma_f32_16x16x32_bf16(pf, vf0, o0, 0, 0, 0);
        o1 = __builtin_amdgcn_mfma_f32_16x16x32_bf16(pf, vf1, o1, 0, 0, 0);
    }

#pragma unroll
    for (int r = 0; r < 4; r++) {
        float s = sums[r];
        s += __shfl_xor(s, 1, 64);
        s += __shfl_xor(s, 2, 64);
        s += __shfl_xor(s, 4, 64);
        s += __shfl_xor(s, 8, 64);
        sums[r] = 1.0f / s;
    }

    const int gi = par >> 1, gj = par & 1;
    const int i0 = pi * 2 + gi;
    bf16_t* ob = outp + ((size_t)i0 * 256 + gj) * 192 + h * 32 + lm;
#pragma unroll
    for (int r = 0; r < 4; r++) {
        int q = lq * 4 + r;
        size_t px = (size_t)(pj0 + q) * 2 * 192;
        ob[px]      = f2bf(o0[r] * sums[r]);
        ob[px + 16] = f2bf(o1[r] * sums[r]);
    }
}

// ---------------------------------------------------------------------------
// Stripe stage 1 v2: 8 sub-lanes per (w,h,n2); sub-lane s handles window
// row s (8 keys), shfl_xor reduce over s. Bias precomputed (b1p). Flat
// softmax, math identical to v1 up to reassociation.
// grid: 1024*6*16*8/256 = 3072 blocks.
// ---------------------------------------------------------------------------
__global__ __launch_bounds__(256) void attn1_k(
    const float* __restrict__ apw,    // (16384,96) fp32
    const bf16_t* __restrict__ qkvs,  // (65536,288) bf16: which*96+h*16+d
    const float* __restrict__ b1p,    // (6,1024): [h][n2*64+m]
    const float* __restrict__ ls1,
    float* __restrict__ x1)           // (1024,6,16,16) fp32
{
    int tid = blockIdx.x * 256 + threadIdx.x;
    int s  = tid & 7;
    int n2 = (tid >> 3) & 15;
    int h  = (tid >> 7) % 6;
    int w  = tid / 768;
    int wi = w >> 5, wj = w & 31;
    float scale = __expf(fminf(ls1[h], 4.605170185988091f));

    int ay = wi * 4 + (n2 >> 2), ax = wj * 4 + (n2 & 3);
    const float* ap = apw + (size_t)(ay * 128 + ax) * 96 + h * 16;
    float qv[16]; float nrm = 0.f;
#pragma unroll
    for (int d = 0; d < 16; d += 4) {
        float4 v = *(const float4*)(ap + d);
        qv[d] = v.x; qv[d + 1] = v.y; qv[d + 2] = v.z; qv[d + 3] = v.w;
        nrm += v.x * v.x + v.y * v.y + v.z * v.z + v.w * v.w;
    }
    float innorm = 1.0f / fmaxf(sqrtf(nrm), 1e-12f);
#pragma unroll
    for (int d = 0; d < 16; d++) qv[d] *= innorm;

    const float* bp = b1p + h * 1024 + n2 * 64 + s * 8;
    int ky = wi * 8 + s;
    const bf16_t* kbase = qkvs + (size_t)(ky * 256 + wj * 8) * 288 + 96 + h * 16;

    float sum = 0.f;
    float acc[16] = {};
#pragma unroll
    for (int j = 0; j < 8; j++) {
        const bf16_t* kp = kbase + j * 288;
        float kv[16];
        ld_bf8(kp, kv); ld_bf8(kp + 8, kv + 8);
        float dot = 0.f, kn = 0.f;
#pragma unroll
        for (int d = 0; d < 16; d++) { dot += qv[d] * kv[d]; kn += kv[d] * kv[d]; }
        dot *= 1.0f / fmaxf(sqrtf(kn), 1e-12f);
        float e = __expf(fmaf(dot, scale, bp[j]));
        sum += e;
        const bf16_t* vp = kp + 96;
        float vv[16];
        ld_bf8(vp, vv); ld_bf8(vp + 8, vv + 8);
#pragma unroll
        for (int d = 0; d < 16; d++) acc[d] += e * vv[d];
    }
    // reduce over the 8 sub-lanes (s = lane&7)
#pragma unroll
    for (int msk = 1; msk < 8; msk <<= 1) {
        sum += __shfl_xor(sum, msk, 64);
#pragma unroll
        for (int d = 0; d < 16; d++) acc[d] += __shfl_xor(acc[d], msk, 64);
    }
    if (s == 0) {
        float inv = 1.0f / sum;
        float* xp = x1 + ((size_t)w * 6 + h) * 256 + n2 * 16;
#pragma unroll
        for (int d = 0; d < 16; d += 4)
            *(float4*)(xp + d) = make_float4(acc[d] * inv, acc[d + 1] * inv,
                                             acc[d + 2] * inv, acc[d + 3] * inv);
    }
}

// Stripe stage 2 -> cat[:, 96:192] (bf16), window-reversed (flat softmax,
// bias precomputed in b2p)
__global__ __launch_bounds__(256) void attn2_k(
    const float* __restrict__ apw,
    const bf16_t* __restrict__ qkvs,
    const float* __restrict__ b2p,    // (6,1024): [h][n1*16+m]
    const float* __restrict__ ls2,
    const float* __restrict__ x1,
    bf16_t* __restrict__ cat)         // (65536,192) bf16, cols 96..191
{
    int tid = blockIdx.x * 256 + threadIdx.x;
    if (tid >= 1024 * 6 * 64) return;
    int n1 = tid & 63;
    int h = (tid >> 6) % 6;
    int w = tid / 384;
    int wi = w >> 5, wj = w & 31;
    float scale = __expf(fminf(ls2[h], 4.605170185988091f));

    int qy = wi * 8 + (n1 >> 3), qx = wj * 8 + (n1 & 7);
    const bf16_t* qp = qkvs + (size_t)(qy * 256 + qx) * 288 + h * 16;
    float qv[16];
    ld_bf8(qp, qv); ld_bf8(qp + 8, qv + 8);
    float nrm = 0.f;
#pragma unroll
    for (int d = 0; d < 16; d++) nrm += qv[d] * qv[d];
    float innorm = 1.0f / fmaxf(sqrtf(nrm), 1e-12f);
#pragma unroll
    for (int d = 0; d < 16; d++) qv[d] *= innorm;

    const float* bp = b2p + h * 1024 + n1 * 16;
    float sum = 0.f;
    float acc[16] = {};
#pragma unroll
    for (int m = 0; m < 16; m++) {
        int ay = wi * 4 + (m >> 2), ax = wj * 4 + (m & 3);
        const float* ap = apw + (size_t)(ay * 128 + ax) * 96 + h * 16;
        float dot = 0.f, kn = 0.f;
#pragma unroll
        for (int d = 0; d < 16; d += 4) {
            float4 v = *(const float4*)(ap + d);
            dot += qv[d] * v.x + qv[d + 1] * v.y + qv[d + 2] * v.z + qv[d + 3] * v.w;
            kn += v.x * v.x + v.y * v.y + v.z * v.z + v.w * v.w;
        }
        dot *= 1.0f / fmaxf(sqrtf(kn), 1e-12f);
        float e = __expf(fmaf(dot, scale, bp[m]));
        sum += e;
        const float* vp = x1 + ((size_t)w * 6 + h) * 256 + m * 16;
#pragma unroll
        for (int d = 0; d < 16; d += 4) {
            float4 v = *(const float4*)(vp + d);
            acc[d] += e * v.x; acc[d + 1] += e * v.y;
            acc[d + 2] += e * v.z; acc[d + 3] += e * v.w;
        }
    }
    float inv = 1.0f / sum;
#pragma unroll
    for (int d = 0; d < 16; d++) acc[d] *= inv;
    bf16_t* op = cat + (size_t)(qy * 256 + qx) * 192 + 96 + h * 16;
    uint4 o0, o1;
    o0.x = pk2(acc[0], acc[1]);   o0.y = pk2(acc[2], acc[3]);
    o0.z = pk2(acc[4], acc[5]);   o0.w = pk2(acc[6], acc[7]);
    o1.x = pk2(acc[8], acc[9]);   o1.y = pk2(acc[10], acc[11]);
    o1.z = pk2(acc[12], acc[13]); o1.w = pk2(acc[14], acc[15]);
    *(uint4*)(op) = o0;
    *(uint4*)(op + 8) = o1;
}

extern "C" void kernel_launch(void* const* d_in, const int* in_sizes, int n_in,
                              void* d_out, int out_size, void* d_ws, size_t ws_size,
                              hipStream_t stream) {
    const float* x          = (const float*)d_in[0];
    const float* table      = (const float*)d_in[3];
    const int*   idx_a2w    = (const int*)d_in[4];
    const int*   idx_w2a    = (const int*)d_in[5];
    const float* qkv_w      = (const float*)d_in[6];
    const float* qkv_b      = (const float*)d_in[7];
    const float* adw_w      = (const float*)d_in[8];
    const float* adw_b      = (const float*)d_in[9];
    const float* apw_w      = (const float*)d_in[10];
    const float* apw_b      = (const float*)d_in[11];
    const float* na_qkv_w   = (const float*)d_in[12];
    const float* na_qkv_b   = (const float*)d_in[13];
    const float* na_after_w = (const float*)d_in[14];
    const float* na_after_b = (const float*)d_in[15];
    const float* na_rpb     = (const float*)d_in[16];
    const float* ls1        = (const float*)d_in[17];
    const float* cpb1_w1    = (const float*)d_in[18];
    const float* cpb1_b1    = (const float*)d_in[19];
    const float* cpb1_w2    = (const float*)d_in[20];
    const float* ls2        = (const float*)d_in[21];
    const float* cpb2_w1    = (const float*)d_in[22];
    const float* cpb2_b1    = (const float*)d_in[23];
    const float* cpb2_w2    = (const float*)d_in[24];
    const float* proj_w     = (const float*)d_in[25];
    const float* proj_b     = (const float*)d_in[26];
    float* out = (float*)d_out;
    (void)in_sizes; (void)n_in; (void)out_size; (void)ws_size;

    // ---- byte-based workspace allocator (256B aligned) ----
    char* base = (char*)d_ws;
    size_t off = 0;
    auto alloc = [&](size_t bytes) {
        off = (off + 255) & ~(size_t)255;
        void* p = base + off; off += bytes; return p;
    };
    float*  bna    = (float*)alloc(576 * 4);
    float*  bt1    = (float*)alloc(225 * 6 * 4);
    float*  bt2    = (float*)alloc(225 * 6 * 4);
    float*  b1p    = (float*)alloc(6144 * 4);
    float*  b2p    = (float*)alloc(6144 * 4);
    float*  qkv_wT = (float*)alloc(288 * 192 * 4);
    bf16_t* Wna_t  = (bf16_t*)alloc(576 * 192 * 2);
    bf16_t* Ws_t   = (bf16_t*)alloc(288 * 192 * 2);
    bf16_t* Waft_t = (bf16_t*)alloc(96 * 192 * 2);
    bf16_t* Wproj_t= (bf16_t*)alloc(192 * 192 * 2);
    bf16_t* qkvs   = (bf16_t*)alloc((size_t)65536 * 288 * 2);  // 37.75 MB
    char*   naR    = (char*)alloc((size_t)65536 * 576 * 2);    // 75.5 MB region
    char*   R      = (char*)alloc((size_t)65536 * 192 * 2);    // 25.2 MB region
    float*  apw    = (float*)alloc((size_t)16384 * 96 * 4);    // 6.3 MB
    // region aliases (strictly sequential lifetimes on the in-order stream):
    bf16_t* naqkv   = (bf16_t*)naR;               // naqkv gemm .. na_attn (planes)
    float*  x1      = (float*)naR;                // attn1 .. attn2 (6.3 MB)
    bf16_t* cat     = (bf16_t*)(naR + (8 << 20)); // na_after .. proj (25.2 MB)
    bf16_t* xb      = (bf16_t*)R;                 // cvt .. naqkv gemm (25.2 MB)
    float*  adw     = (float*)R;                  // dwconv .. apw gemm (12.6 MB)
    bf16_t* xna_pre = (bf16_t*)R;                 // na_attn .. na_after (25.2 MB)

    // Tiny precomputes (independent)
    tpose_qkvw_k<<<216, 256, 0, stream>>>(qkv_w, qkv_wT);
    fold_wna_t_k<<<432, 256, 0, stream>>>(qkv_wT, na_qkv_w, Wna_t);
    fold_bna_k<<<3, 256, 0, stream>>>(qkv_b, na_qkv_w, na_qkv_b, bna);
    cpb_k<<<6, 256, 0, stream>>>(table, cpb1_w1, cpb1_b1, cpb1_w2, bt1);
    cpb_k<<<6, 256, 0, stream>>>(table, cpb2_w1, cpb2_b1, cpb2_w2, bt2);
    sigb_k<<<24, 256, 0, stream>>>(bt1, idx_a2w, b1p);
    sigb_k<<<24, 256, 0, stream>>>(bt2, idx_w2a, b2p);
    tcvt_k<<<216, 256, 0, stream>>>(qkv_w, Ws_t, 192, 288, 576, 288);
    tcvt_k<<<72, 256, 0, stream>>>(na_after_w, Waft_t, 192, 96, 96, 0);
    tcvt_k<<<144, 256, 0, stream>>>(proj_w, Wproj_t, 192, 192, 192, 0);
    cvt_bf16_k<<<6144, 256, 0, stream>>>(x, xb, 65536 * 192 / 8);

    // Stripe qkv: xb @ Ws_t^T + b -> qkvs bf16 (65536,288), row-major
    mfma_gemm_k<192, 0, bf16_t><<<dim3(3, 512), 256, 0, stream>>>(
        xb, Ws_t, qkv_b + 288, qkvs, 192, 192, 288);

    // Folded NA qkv: xb @ Wna_t^T + bna -> naqkv bf16 parity-split planes
    mfma_gemm_k<192, 1, bf16_t><<<dim3(6, 512), 256, 0, stream>>>(
        xb, Wna_t, bna, naqkv, 192, 192, 576);

    // Anchor: depthwise conv (xb dead -> adw in R), pointwise GEMM -> apw
    dwconv_k<<<3072, 256, 0, stream>>>(x, adw_w, adw_b, adw);
    gemm_k<float, float><<<dim3(2, 256), 256, 0, stream>>>(
        adw, apw_w, apw_b, apw, 16384, 96, 192, 192, 96, 96);

    // Neighborhood attention (adw dead -> xna_pre in R)
    na_attn_k<<<dim3(2, 128, 24), 256, 0, stream>>>(naqkv, na_rpb, xna_pre);

    // na_after: xna_pre @ Waft_t^T + b -> cat[:,0:96]  (naqkv dead)
    mfma_gemm_k<192, 0, bf16_t><<<dim3(1, 512), 256, 0, stream>>>(
        xna_pre, Waft_t, na_after_b, cat, 192, 192, 192);

    // Stripe attention -> x1, then cat[:,96:192]
    attn1_k<<<3072, 256, 0, stream>>>(apw, qkvs, b1p, ls1, x1);
    attn2_k<<<1536, 256, 0, stream>>>(apw, qkvs, b2p, ls2, x1, cat);

    // Final projection: cat @ Wproj_t^T + proj_b -> out fp32
    mfma_gemm_k<192, 0, float><<<dim3(2, 512), 256, 0, stream>>>(
        cat, Wproj_t, proj_b, out, 192, 192, 192);
}

// Round 3
// 600.794 us; speedup vs baseline: 1.2022x; 1.1094x over previous
//
#include <hip/hip_runtime.h>
#include <math.h>

// ---------------------------------------------------------------------------
// MixedAttention: H=W=256, C=192, HEADS=6, NA: K=7 DIL=2 hd=32,
// stripe: WS=8 AWS=4 hs=16, 1024 windows.
// R10: MFMA attn1. One wave = one (window, head): S^T = K(64x16)@A^T via
// 4x mfma_16x16x32_bf16 (k-dim zero-padded 16->32), flat softmax in-register
// (anchor norm folded into scale; K pre-normalized fp32->bf16), P packed via
// v_cvt_pk -> per-wave LDS -> PV mfma (keys are the contraction dim, 2x
// mfma 16x16x32). Bias staged in LDS from transposed b1pT. Block = 4 windows
// x same head -> 6144 waves, ~24 waves/CU (was: 79us @ 10.9% occ, VGPR 144,
// all pipes idle).
// ---------------------------------------------------------------------------

typedef unsigned short bf16_t;
typedef __attribute__((ext_vector_type(8))) short short8;   // MFMA A/B frag (8 bf16)
typedef __attribute__((ext_vector_type(4))) float f32x4;    // MFMA C/D frag

__device__ inline float bf2f(bf16_t v) { return __uint_as_float((unsigned)v << 16); }
__device__ inline bf16_t f2bf(float f) {
    unsigned u = __float_as_uint(f);
    unsigned r = (u + 0x7fffu + ((u >> 16) & 1u)) >> 16;   // RNE, finite inputs
    return (bf16_t)r;
}
__device__ inline float cvt(float v) { return v; }
__device__ inline float cvt(bf16_t v) { return bf2f(v); }
__device__ inline void sto(float* p, float v) { *p = v; }
__device__ inline void sto(bf16_t* p, float v) { *p = f2bf(v); }

// load 8 consecutive bf16 (16B aligned) -> 8 floats
__device__ inline void ld_bf8(const bf16_t* p, float* d) {
    uint4 r = *(const uint4*)p;
    d[0] = __uint_as_float(r.x << 16); d[1] = __uint_as_float(r.x & 0xffff0000u);
    d[2] = __uint_as_float(r.y << 16); d[3] = __uint_as_float(r.y & 0xffff0000u);
    d[4] = __uint_as_float(r.z << 16); d[5] = __uint_as_float(r.z & 0xffff0000u);
    d[6] = __uint_as_float(r.w << 16); d[7] = __uint_as_float(r.w & 0xffff0000u);
}
__device__ inline unsigned pk2(float a, float b) {
    return (unsigned)f2bf(a) | ((unsigned)f2bf(b) << 16);
}

// ---------------------------------------------------------------------------
// MFMA GEMM: C[M,N] = A[M,K]bf16 @ Bt[N,K]^T + bias. Tile 128x96, 4 waves,
// each wave 64x48 = 4x3 16x16 frags, K=192 fully unrolled, no LDS.
// NA=1: scatter-store into parity-split head planes.
// ---------------------------------------------------------------------------
template <int KD, int NA, typename TO>
__global__ __launch_bounds__(256) void mfma_gemm_k(
    const bf16_t* __restrict__ A, const bf16_t* __restrict__ Bt,
    const float* __restrict__ bias, TO* __restrict__ C,
    int lda, int ldb, int ldc)
{
    const int t = threadIdx.x;
    const int lane = t & 63, wave = t >> 6;
    const int wr = wave >> 1, wc = wave & 1;
    const int m0 = blockIdx.y * 128 + wr * 64;
    const int n0 = blockIdx.x * 96 + wc * 48;
    const int lm = lane & 15;
    const int q  = lane >> 4;

    f32x4 acc[4][3] = {};
    const bf16_t* ap = A + (size_t)(m0 + lm) * lda + q * 8;
    const bf16_t* bp = Bt + (size_t)(n0 + lm) * ldb + q * 8;

#pragma unroll
    for (int k0 = 0; k0 < KD; k0 += 32) {
        short8 af[4], bf[3];
#pragma unroll
        for (int mi = 0; mi < 4; mi++)
            af[mi] = *(const short8*)(ap + (size_t)(mi * 16) * lda + k0);
#pragma unroll
        for (int ni = 0; ni < 3; ni++)
            bf[ni] = *(const short8*)(bp + (size_t)(ni * 16) * ldb + k0);
#pragma unroll
        for (int mi = 0; mi < 4; mi++)
#pragma unroll
            for (int ni = 0; ni < 3; ni++)
                acc[mi][ni] = __builtin_amdgcn_mfma_f32_16x16x32_bf16(
                    af[mi], bf[ni], acc[mi][ni], 0, 0, 0);
    }

#pragma unroll
    for (int mi = 0; mi < 4; mi++) {
#pragma unroll
        for (int ni = 0; ni < 3; ni++) {
            int col = n0 + ni * 16 + lm;
            float bv = bias[col];
            if (NA) {
                int which = col / 192;
                int hh = (col % 192) / 32;
                int d  = col % 32;
                size_t pbase = ((size_t)which * 6 + hh) * ((size_t)65536 * 32) + d;
#pragma unroll
                for (int r = 0; r < 4; r++) {
                    int row = m0 + mi * 16 + q * 4 + r;
                    int ii = row >> 8, jj = row & 255;
                    int par = ((ii & 1) << 1) | (jj & 1);
                    int pix = par * 16384 + (ii >> 1) * 128 + (jj >> 1);
                    sto(&C[pbase + (size_t)pix * 32], acc[mi][ni][r] + bv);
                }
            } else {
#pragma unroll
                for (int r = 0; r < 4; r++) {
                    int row = m0 + mi * 16 + q * 4 + r;
                    sto(&C[(size_t)row * ldc + col], acc[mi][ni][r] + bv);
                }
            }
        }
    }
}

// x fp32 -> bf16, 8 elems/thread
__global__ __launch_bounds__(256) void cvt_bf16_k(
    const float* __restrict__ src, bf16_t* __restrict__ dst, int n8)
{
    int tid = blockIdx.x * 256 + threadIdx.x;
    if (tid >= n8) return;
    float4 a = ((const float4*)src)[tid * 2];
    float4 b = ((const float4*)src)[tid * 2 + 1];
    uint4 o;
    o.x = pk2(a.x, a.y); o.y = pk2(a.z, a.w);
    o.z = pk2(b.x, b.y); o.w = pk2(b.z, b.w);
    ((uint4*)dst)[tid] = o;
}

// Wt[n*Kd + k] = (bf16) W[k*ld + coloff + n]   (transpose + convert)
__global__ __launch_bounds__(256) void tcvt_k(
    const float* __restrict__ W, bf16_t* __restrict__ Wt,
    int Kd, int N, int ld, int coloff)
{
    int tid = blockIdx.x * 256 + threadIdx.x;
    if (tid >= Kd * N) return;
    int k = tid % Kd, n = tid / Kd;
    Wt[tid] = f2bf(W[(size_t)k * ld + coloff + n]);
}

// qkv_wT[j*192 + k] = qkv_w[k*576 + j], j < 288
__global__ __launch_bounds__(256) void tpose_qkvw_k(
    const float* __restrict__ W, float* __restrict__ WT)
{
    int tid = blockIdx.x * 256 + threadIdx.x;
    if (tid >= 288 * 192) return;
    int k = tid % 192, j = tid / 192;
    WT[tid] = W[(size_t)k * 576 + j];
}

// Wna_t[n*192 + k] = (bf16) sum_j qkv_wT[j,k] * na_qkv_w[j,n], j<288
__global__ __launch_bounds__(256) void fold_wna_t_k(
    const float* __restrict__ qkv_wT, const float* __restrict__ na_qkv_w,
    bf16_t* __restrict__ Wna_t)
{
    int tid = blockIdx.x * 256 + threadIdx.x;
    if (tid >= 576 * 192) return;
    int k = tid % 192, n = tid / 192;
    float acc = 0.f;
    for (int j = 0; j < 288; j++)
        acc += qkv_wT[j * 192 + k] * na_qkv_w[j * 576 + n];
    Wna_t[tid] = f2bf(acc);
}

__global__ __launch_bounds__(256) void fold_bna_k(
    const float* __restrict__ qkv_b, const float* __restrict__ na_qkv_w,
    const float* __restrict__ na_qkv_b, float* __restrict__ bna)
{
    int j = blockIdx.x * 256 + threadIdx.x;
    if (j >= 576) return;
    float acc = na_qkv_b[j];
    for (int k = 0; k < 288; k++)
        acc += qkv_b[k] * na_qkv_w[k * 576 + j];
    bna[j] = acc;
}

// bt[t,h] = (relu(table(225,2) @ w1 + b1) @ w2)[t,h]
__global__ __launch_bounds__(256) void cpb_k(
    const float* __restrict__ table, const float* __restrict__ w1,
    const float* __restrict__ b1, const float* __restrict__ w2,
    float* __restrict__ bt)
{
    int tid = blockIdx.x * 256 + threadIdx.x;
    if (tid >= 225 * 6) return;
    int h = tid % 6, t = tid / 6;
    float t0 = table[t * 2], t1 = table[t * 2 + 1];
    float acc = 0.f;
    for (int m = 0; m < 512; m++) {
        float hv = t0 * w1[m] + t1 * w1[512 + m] + b1[m];
        hv = fmaxf(hv, 0.f);
        acc += hv * w2[m * 6 + h];
    }
    bt[tid] = acc;
}

// b2p[h*1024 + n1*16 + m] = 16*sigmoid(bt[idx[n1*16+m]*6 + h])  (attn2)
__global__ __launch_bounds__(256) void sigb_k(
    const float* __restrict__ bt, const int* __restrict__ idx,
    float* __restrict__ bp)
{
    int tid = blockIdx.x * 256 + threadIdx.x;
    if (tid >= 6144) return;
    int h = tid >> 10, p = tid & 1023;
    bp[tid] = 16.0f / (1.0f + __expf(-bt[idx[p] * 6 + h]));
}

// b1pT[h*1024 + m*16 + n2] = 16*sigmoid(bt[idx[n2*64+m]*6 + h])  (attn1,
// transposed so the MFMA kernel reads [key][anchor])
__global__ __launch_bounds__(256) void sigb1T_k(
    const float* __restrict__ bt, const int* __restrict__ idx,
    float* __restrict__ bp)
{
    int tid = blockIdx.x * 256 + threadIdx.x;
    if (tid >= 6144) return;
    int h = tid >> 10, p = tid & 1023;
    int m = p >> 4, n2 = p & 15;
    bp[tid] = 16.0f / (1.0f + __expf(-bt[idx[n2 * 64 + m] * 6 + h]));
}

// legacy fp32 tiled GEMM (kept for the small anchor-pointwise GEMM)
#define BM 64
#define BN 64
#define BKK 16
template <typename TA, typename TO>
__global__ __launch_bounds__(256) void gemm_k(
    const TA* __restrict__ A, const float* __restrict__ B,
    const float* __restrict__ bias, TO* __restrict__ C,
    int M, int N, int Kd, int lda, int ldb, int ldc)
{
    __shared__ float As[BKK][BM + 1];
    __shared__ float Bs[BKK][BN + 1];
    const int t  = threadIdx.x;
    const int tx = t & 15, ty = t >> 4;
    const int m0 = blockIdx.y * BM, n0 = blockIdx.x * BN;
    float acc[4][4] = {};

    for (int k0 = 0; k0 < Kd; k0 += BKK) {
#pragma unroll
        for (int i = 0; i < 4; i++) {
            int m = (t >> 4) + i * 16;
            int k = t & 15;
            int gm = m0 + m, gk = k0 + k;
            As[k][m] = (gm < M && gk < Kd) ? cvt(A[(size_t)gm * lda + gk]) : 0.f;
        }
#pragma unroll
        for (int i = 0; i < 4; i++) {
            int k = (t >> 6) + i * 4;
            int n = t & 63;
            int gk = k0 + k, gn = n0 + n;
            Bs[k][n] = (gk < Kd && gn < N) ? B[(size_t)gk * ldb + gn] : 0.f;
        }
        __syncthreads();
#pragma unroll
        for (int k = 0; k < BKK; k++) {
            float a[4], b[4];
#pragma unroll
            for (int i = 0; i < 4; i++) a[i] = As[k][ty * 4 + i];
#pragma unroll
            for (int j = 0; j < 4; j++) b[j] = Bs[k][tx * 4 + j];
#pragma unroll
            for (int i = 0; i < 4; i++)
#pragma unroll
                for (int j = 0; j < 4; j++) acc[i][j] += a[i] * b[j];
        }
        __syncthreads();
    }
#pragma unroll
    for (int i = 0; i < 4; i++) {
        int gm = m0 + ty * 4 + i;
        if (gm >= M) continue;
#pragma unroll
        for (int j = 0; j < 4; j++) {
            int gn = n0 + tx * 4 + j;
            if (gn >= N) continue;
            sto(&C[(size_t)gm * ldc + gn], acc[i][j] + bias[gn]);
        }
    }
}

// Depthwise 3x3 stride-2 pad-1 on x (256,256,192) -> adw (128,128,192) fp32
__global__ __launch_bounds__(256) void dwconv_k(
    const float* __restrict__ x, const float* __restrict__ w,
    const float* __restrict__ b, float* __restrict__ adw)
{
    int tid = blockIdx.x * 256 + threadIdx.x;
    if (tid >= 16384 * 48) return;
    int c4 = tid % 48;
    int p = tid / 48;
    int ow = p & 127, oh = p >> 7;
    int c = c4 * 4;
    float4 s = *(const float4*)(b + c);
#pragma unroll
    for (int kh = 0; kh < 3; kh++) {
        int ih = oh * 2 - 1 + kh;
        if (ih < 0 || ih >= 256) continue;
#pragma unroll
        for (int kw = 0; kw < 3; kw++) {
            int iw = ow * 2 - 1 + kw;
            if (iw < 0 || iw >= 256) continue;
            float4 xv = *(const float4*)(x + (size_t)(ih * 256 + iw) * 192 + c);
            float4 wv = *(const float4*)(w + (kh * 3 + kw) * 192 + c);
            s.x += xv.x * wv.x; s.y += xv.y * wv.y;
            s.z += xv.z * wv.z; s.w += xv.w * wv.w;
        }
    }
    *(float4*)(adw + (size_t)p * 192 + c) = s;
}

// ---------------------------------------------------------------------------
// Neighborhood attention v6: MFMA (unchanged from R8, verified).
// ---------------------------------------------------------------------------
__global__ __launch_bounds__(256) void na_attn_k(
    const bf16_t* __restrict__ nap, const float* __restrict__ rpb,
    bf16_t* __restrict__ outp)
{
    __shared__ float rpb_s[176];
    __shared__ __align__(16) unsigned P_s[4][16][20];   // [wave][q][slot-pair]

    const int t = threadIdx.x;
    const int wv = t >> 6, lane = t & 63;
    const int lm = lane & 15, lq = lane >> 4;
    const int z = blockIdx.z;
    const int h = z >> 2, par = z & 3;

    if (t < 169) rpb_s[t] = rpb[h * 169 + t];
    __syncthreads();

    const int pi  = blockIdx.y;
    const int pj0 = blockIdx.x * 64 + wv * 16;
    const int si  = min(max(pi - 3, 0), 121);
    const int rbh0 = si - pi + 6;
    const int c0  = min(max(pj0 - 3, 0), 121) & ~7;

    const size_t plane = (size_t)65536 * 32;
    const size_t poff  = (size_t)(par * 16384) * 32;
    const bf16_t* qpl = nap + (size_t)h * plane + poff;
    const bf16_t* kpl = nap + (size_t)(6 + h) * plane + poff;
    const bf16_t* vpl = nap + (size_t)(12 + h) * plane + poff;

    const short8 qf = *(const short8*)(qpl + ((size_t)(pi * 128 + pj0 + lm)) * 32 + lq * 8);

    int offc[4][2]; bool vm[4][2];
#pragma unroll
    for (int r = 0; r < 4; r++) {
        int q = lq * 4 + r, pj = pj0 + q;
        int sj = min(max(pj - 3, 0), 121);
#pragma unroll
        for (int t2 = 0; t2 < 2; t2++) {
            int c = c0 + 2 * lm + t2;
            vm[r][t2] = (c >= sj) && (c <= sj + 6);
            offc[r][t2] = min(max(c - pj + 6, 0), 12);
        }
    }
    const int kc0 = min(c0 + 2 * lm,     127) * 64;   // byte offsets (64B/px)
    const int kc1 = min(c0 + 2 * lm + 1, 127) * 64;
    int vcoff[8];
#pragma unroll
    for (int i = 0; i < 8; i++) vcoff[i] = min(c0 + lq * 8 + i, 127) * 64;

    const float scale = 0.17677669529663687f; // 32^-0.5
    f32x4 o0 = {}, o1 = {};
    float sums[4] = {0.f, 0.f, 0.f, 0.f};
    const f32x4 zz = {};

#pragma unroll 2
    for (int rr = 0; rr < 7; rr++) {
        const size_t rb2 = (size_t)((si + rr) * 128) * 64;  // row base, bytes
        const char* krow = (const char*)kpl + rb2;
        const char* vrow = (const char*)vpl + rb2;

        short8 kf0 = *(const short8*)(krow + kc0 + lq * 16);
        short8 kf1 = *(const short8*)(krow + kc1 + lq * 16);
        f32x4 s0 = __builtin_amdgcn_mfma_f32_16x16x32_bf16(qf, kf0, zz, 0, 0, 0);
        f32x4 s1 = __builtin_amdgcn_mfma_f32_16x16x32_bf16(qf, kf1, zz, 0, 0, 0);

        const float* br = rpb_s + (rbh0 + rr) * 13;
        float e0[4], e1[4];
#pragma unroll
        for (int r = 0; r < 4; r++) {
            float a0 = __expf(fmaf(s0[r], scale, br[offc[r][0]]));
            float a1 = __expf(fmaf(s1[r], scale, br[offc[r][1]]));
            a0 = vm[r][0] ? a0 : 0.f;
            a1 = vm[r][1] ? a1 : 0.f;
            e0[r] = a0; e1[r] = a1;
            sums[r] += a0 + a1;
        }
#pragma unroll
        for (int r = 0; r < 4; r++) {
            unsigned pr;
            asm("v_cvt_pk_bf16_f32 %0, %1, %2" : "=v"(pr) : "v"(e0[r]), "v"(e1[r]));
            P_s[wv][lq * 4 + r][lm] = pr;   // slots 2lm (lo), 2lm+1 (hi)
        }
        const short8 pf = *(const short8*)((const bf16_t*)P_s[wv][lm] + lq * 8);

        short8 vf0, vf1;
        const char* v0b = vrow + lm * 2;
        const char* v1b = vrow + 32 + lm * 2;
#pragma unroll
        for (int i = 0; i < 8; i++) {
            ((bf16_t*)&vf0)[i] = *(const bf16_t*)(v0b + vcoff[i]);
            ((bf16_t*)&vf1)[i] = *(const bf16_t*)(v1b + vcoff[i]);
        }
        o0 = __builtin_amdgcn_mfma_f32_16x16x32_bf16(pf, vf0, o0, 0, 0, 0);
        o1 = __builtin_amdgcn_mfma_f32_16x16x32_bf16(pf, vf1, o1, 0, 0, 0);
    }

#pragma unroll
    for (int r = 0; r < 4; r++) {
        float s = sums[r];
        s += __shfl_xor(s, 1, 64);
        s += __shfl_xor(s, 2, 64);
        s += __shfl_xor(s, 4, 64);
        s += __shfl_xor(s, 8, 64);
        sums[r] = 1.0f / s;
    }

    const int gi = par >> 1, gj = par & 1;
    const int i0 = pi * 2 + gi;
    bf16_t* ob = outp + ((size_t)i0 * 256 + gj) * 192 + h * 32 + lm;
#pragma unroll
    for (int r = 0; r < 4; r++) {
        int q = lq * 4 + r;
        size_t px = (size_t)(pj0 + q) * 2 * 192;
        ob[px]      = f2bf(o0[r] * sums[r]);
        ob[px + 16] = f2bf(o1[r] * sums[r]);
    }
}

// ---------------------------------------------------------------------------
// Stripe stage 1 v3 (MFMA): one wave = one (window, head).
// S^T tile t: D = K_norm(16x16,k-pad32) @ A_bf^T -> lane: anchor=lm,
// keys lq*4+r. Flat softmax with bias from LDS (b1pT). P packed bf16 ->
// per-wave LDS [anchor][key] -> PV A-frag directly; V B-frag via 2B gathers.
// X1 out: lane holds d=lm, anchors lq*4+r.
// grid (256, 6), block 256 = 4 waves = 4 windows of the same head.
// ---------------------------------------------------------------------------
__global__ __launch_bounds__(256) void attn1_k(
    const float* __restrict__ apw,    // (16384,96) fp32
    const bf16_t* __restrict__ qkvs,  // (65536,288) bf16
    const float* __restrict__ b1pT,   // (6,1024): [h][m*16+n2]
    const float* __restrict__ ls1,
    float* __restrict__ x1)           // (1024,6,16,16) fp32
{
    __shared__ float bT_s[1024];
    __shared__ __align__(16) unsigned P_s[4][16][36];  // stride 36 u32: 16B-align + bank spread

    const int t = threadIdx.x;
    const int wv = t >> 6, lane = t & 63;
    const int lm = lane & 15, lq = lane >> 4;
    const int h = blockIdx.y;
    const int w = blockIdx.x * 4 + wv;
    const int wi = w >> 5, wj = w & 31;

#pragma unroll
    for (int i = 0; i < 4; i++) bT_s[i * 256 + t] = b1pT[h * 1024 + i * 256 + t];
    __syncthreads();

    const float scale = __expf(fminf(ls1[h], 4.605170185988091f));

    // ---- anchors -> B-frag (col=anchor=lm, k=d=lq*8+i; d<16 so lq<2) ----
    short8 af = {};
    float an2 = 0.f;
    {
        int ay = wi * 4 + (lm >> 2), ax = wj * 4 + (lm & 3);
        const float* ap = apw + (size_t)(ay * 128 + ax) * 96 + h * 16;
        if (lq < 2) {
            float4 v0 = *(const float4*)(ap + lq * 8);
            float4 v1 = *(const float4*)(ap + lq * 8 + 4);
            float vs[8] = {v0.x, v0.y, v0.z, v0.w, v1.x, v1.y, v1.z, v1.w};
            unsigned* au = (unsigned*)&af;
#pragma unroll
            for (int j2 = 0; j2 < 4; j2++) {
                unsigned u = pk2(vs[2 * j2], vs[2 * j2 + 1]);
                au[j2] = u;
                float lo = __uint_as_float(u << 16);
                float hi = __uint_as_float(u & 0xffff0000u);
                an2 += lo * lo + hi * hi;   // norm of the ROUNDED anchor
            }
        }
    }
    an2 += __shfl_xor(an2, 16, 64);
    an2 += __shfl_xor(an2, 32, 64);
    const float sa = scale / fmaxf(sqrtf(an2), 1e-12f);  // fold anchor norm

    const f32x4 zz = {};
    f32x4 o = {};
    float sum = 0.f;

#pragma unroll
    for (int g = 0; g < 2; g++) {
#pragma unroll
        for (int tt = 0; tt < 2; tt++) {
            const int tile = g * 2 + tt;
            // K tile -> A-frag (row=key=tile*16+lm, k=d), fp32-normalized, re-rounded
            int py = wi * 8 + tile * 2 + (lm >> 3);
            int px = wj * 8 + (lm & 7);
            const bf16_t* kp = qkvs + (size_t)(py * 256 + px) * 288 + 96 + h * 16;
            short8 kf = {};
            float kn2 = 0.f;
            float klo[4], khi[4];
            if (lq < 2) {
                uint4 kr = *(const uint4*)(kp + lq * 8);
                unsigned ku[4] = {kr.x, kr.y, kr.z, kr.w};
#pragma unroll
                for (int j2 = 0; j2 < 4; j2++) {
                    klo[j2] = __uint_as_float(ku[j2] << 16);
                    khi[j2] = __uint_as_float(ku[j2] & 0xffff0000u);
                    kn2 += klo[j2] * klo[j2] + khi[j2] * khi[j2];
                }
            }
            kn2 += __shfl_xor(kn2, 16, 64);
            kn2 += __shfl_xor(kn2, 32, 64);
            float rk = 1.0f / fmaxf(sqrtf(kn2), 1e-12f);
            if (lq < 2) {
                unsigned* kuo = (unsigned*)&kf;
#pragma unroll
                for (int j2 = 0; j2 < 4; j2++)
                    kuo[j2] = pk2(klo[j2] * rk, khi[j2] * rk);
            }
            f32x4 s = __builtin_amdgcn_mfma_f32_16x16x32_bf16(kf, af, zz, 0, 0, 0);
            float e[4];
#pragma unroll
            for (int r = 0; r < 4; r++) {
                e[r] = __expf(fmaf(s[r], sa,
                              bT_s[((tile * 16 + lq * 4 + r) << 4) + lm]));
                sum += e[r];
            }
            P_s[wv][lm][tile * 8 + lq * 2]     = pk2(e[0], e[1]);
            P_s[wv][lm][tile * 8 + lq * 2 + 1] = pk2(e[2], e[3]);
        }
        // ---- PV for keys g*32 .. g*32+31 ----
        const short8 pf = *(const short8*)&P_s[wv][lm][g * 16 + lq * 4];
        short8 vf;
        int pyv = wi * 8 + g * 4 + lq;
        const bf16_t* vrow = qkvs + (size_t)(pyv * 256 + wj * 8) * 288 + 192 + h * 16 + lm;
#pragma unroll
        for (int i = 0; i < 8; i++)
            ((bf16_t*)&vf)[i] = vrow[(size_t)i * 288];
        o = __builtin_amdgcn_mfma_f32_16x16x32_bf16(pf, vf, o, 0, 0, 0);
    }

    sum += __shfl_xor(sum, 16, 64);
    sum += __shfl_xor(sum, 32, 64);
    const float inv = 1.0f / sum;
    float* xp = x1 + ((size_t)w * 6 + h) * 256;
#pragma unroll
    for (int r = 0; r < 4; r++) {
        float iv = __shfl(inv, lq * 4 + r, 64);   // inv for anchor lq*4+r
        xp[(lq * 4 + r) * 16 + lm] = o[r] * iv;
    }
}

// Stripe stage 2 -> cat[:, 96:192] (bf16), window-reversed (flat softmax,
// bias precomputed in b2p)
__global__ __launch_bounds__(256) void attn2_k(
    const float* __restrict__ apw,
    const bf16_t* __restrict__ qkvs,
    const float* __restrict__ b2p,    // (6,1024): [h][n1*16+m]
    const float* __restrict__ ls2,
    const float* __restrict__ x1,
    bf16_t* __restrict__ cat)         // (65536,192) bf16, cols 96..191
{
    int tid = blockIdx.x * 256 + threadIdx.x;
    if (tid >= 1024 * 6 * 64) return;
    int n1 = tid & 63;
    int h = (tid >> 6) % 6;
    int w = tid / 384;
    int wi = w >> 5, wj = w & 31;
    float scale = __expf(fminf(ls2[h], 4.605170185988091f));

    int qy = wi * 8 + (n1 >> 3), qx = wj * 8 + (n1 & 7);
    const bf16_t* qp = qkvs + (size_t)(qy * 256 + qx) * 288 + h * 16;
    float qv[16];
    ld_bf8(qp, qv); ld_bf8(qp + 8, qv + 8);
    float nrm = 0.f;
#pragma unroll
    for (int d = 0; d < 16; d++) nrm += qv[d] * qv[d];
    float innorm = 1.0f / fmaxf(sqrtf(nrm), 1e-12f);
#pragma unroll
    for (int d = 0; d < 16; d++) qv[d] *= innorm;

    const float* bp = b2p + h * 1024 + n1 * 16;
    float sum = 0.f;
    float acc[16] = {};
#pragma unroll
    for (int m = 0; m < 16; m++) {
        int ay = wi * 4 + (m >> 2), ax = wj * 4 + (m & 3);
        const float* ap = apw + (size_t)(ay * 128 + ax) * 96 + h * 16;
        float dot = 0.f, kn = 0.f;
#pragma unroll
        for (int d = 0; d < 16; d += 4) {
            float4 v = *(const float4*)(ap + d);
            dot += qv[d] * v.x + qv[d + 1] * v.y + qv[d + 2] * v.z + qv[d + 3] * v.w;
            kn += v.x * v.x + v.y * v.y + v.z * v.z + v.w * v.w;
        }
        dot *= 1.0f / fmaxf(sqrtf(kn), 1e-12f);
        float e = __expf(fmaf(dot, scale, bp[m]));
        sum += e;
        const float* vp = x1 + ((size_t)w * 6 + h) * 256 + m * 16;
#pragma unroll
        for (int d = 0; d < 16; d += 4) {
            float4 v = *(const float4*)(vp + d);
            acc[d] += e * v.x; acc[d + 1] += e * v.y;
            acc[d + 2] += e * v.z; acc[d + 3] += e * v.w;
        }
    }
    float inv = 1.0f / sum;
#pragma unroll
    for (int d = 0; d < 16; d++) acc[d] *= inv;
    bf16_t* op = cat + (size_t)(qy * 256 + qx) * 192 + 96 + h * 16;
    uint4 o0, o1;
    o0.x = pk2(acc[0], acc[1]);   o0.y = pk2(acc[2], acc[3]);
    o0.z = pk2(acc[4], acc[5]);   o0.w = pk2(acc[6], acc[7]);
    o1.x = pk2(acc[8], acc[9]);   o1.y = pk2(acc[10], acc[11]);
    o1.z = pk2(acc[12], acc[13]); o1.w = pk2(acc[14], acc[15]);
    *(uint4*)(op) = o0;
    *(uint4*)(op + 8) = o1;
}

extern "C" void kernel_launch(void* const* d_in, const int* in_sizes, int n_in,
                              void* d_out, int out_size, void* d_ws, size_t ws_size,
                              hipStream_t stream) {
    const float* x          = (const float*)d_in[0];
    const float* table      = (const float*)d_in[3];
    const int*   idx_a2w    = (const int*)d_in[4];
    const int*   idx_w2a    = (const int*)d_in[5];
    const float* qkv_w      = (const float*)d_in[6];
    const float* qkv_b      = (const float*)d_in[7];
    const float* adw_w      = (const float*)d_in[8];
    const float* adw_b      = (const float*)d_in[9];
    const float* apw_w      = (const float*)d_in[10];
    const float* apw_b      = (const float*)d_in[11];
    const float* na_qkv_w   = (const float*)d_in[12];
    const float* na_qkv_b   = (const float*)d_in[13];
    const float* na_after_w = (const float*)d_in[14];
    const float* na_after_b = (const float*)d_in[15];
    const float* na_rpb     = (const float*)d_in[16];
    const float* ls1        = (const float*)d_in[17];
    const float* cpb1_w1    = (const float*)d_in[18];
    const float* cpb1_b1    = (const float*)d_in[19];
    const float* cpb1_w2    = (const float*)d_in[20];
    const float* ls2        = (const float*)d_in[21];
    const float* cpb2_w1    = (const float*)d_in[22];
    const float* cpb2_b1    = (const float*)d_in[23];
    const float* cpb2_w2    = (const float*)d_in[24];
    const float* proj_w     = (const float*)d_in[25];
    const float* proj_b     = (const float*)d_in[26];
    float* out = (float*)d_out;
    (void)in_sizes; (void)n_in; (void)out_size; (void)ws_size;

    // ---- byte-based workspace allocator (256B aligned) ----
    char* base = (char*)d_ws;
    size_t off = 0;
    auto alloc = [&](size_t bytes) {
        off = (off + 255) & ~(size_t)255;
        void* p = base + off; off += bytes; return p;
    };
    float*  bna    = (float*)alloc(576 * 4);
    float*  bt1    = (float*)alloc(225 * 6 * 4);
    float*  bt2    = (float*)alloc(225 * 6 * 4);
    float*  b1pT   = (float*)alloc(6144 * 4);
    float*  b2p    = (float*)alloc(6144 * 4);
    float*  qkv_wT = (float*)alloc(288 * 192 * 4);
    bf16_t* Wna_t  = (bf16_t*)alloc(576 * 192 * 2);
    bf16_t* Ws_t   = (bf16_t*)alloc(288 * 192 * 2);
    bf16_t* Waft_t = (bf16_t*)alloc(96 * 192 * 2);
    bf16_t* Wproj_t= (bf16_t*)alloc(192 * 192 * 2);
    bf16_t* qkvs   = (bf16_t*)alloc((size_t)65536 * 288 * 2);  // 37.75 MB
    char*   naR    = (char*)alloc((size_t)65536 * 576 * 2);    // 75.5 MB region
    char*   R      = (char*)alloc((size_t)65536 * 192 * 2);    // 25.2 MB region
    float*  apw    = (float*)alloc((size_t)16384 * 96 * 4);    // 6.3 MB
    // region aliases (strictly sequential lifetimes on the in-order stream):
    bf16_t* naqkv   = (bf16_t*)naR;               // naqkv gemm .. na_attn (planes)
    float*  x1      = (float*)naR;                // attn1 .. attn2 (6.3 MB)
    bf16_t* cat     = (bf16_t*)(naR + (8 << 20)); // na_after .. proj (25.2 MB)
    bf16_t* xb      = (bf16_t*)R;                 // cvt .. naqkv gemm (25.2 MB)
    float*  adw     = (float*)R;                  // dwconv .. apw gemm (12.6 MB)
    bf16_t* xna_pre = (bf16_t*)R;                 // na_attn .. na_after (25.2 MB)

    // Tiny precomputes (independent)
    tpose_qkvw_k<<<216, 256, 0, stream>>>(qkv_w, qkv_wT);
    fold_wna_t_k<<<432, 256, 0, stream>>>(qkv_wT, na_qkv_w, Wna_t);
    fold_bna_k<<<3, 256, 0, stream>>>(qkv_b, na_qkv_w, na_qkv_b, bna);
    cpb_k<<<6, 256, 0, stream>>>(table, cpb1_w1, cpb1_b1, cpb1_w2, bt1);
    cpb_k<<<6, 256, 0, stream>>>(table, cpb2_w1, cpb2_b1, cpb2_w2, bt2);
    sigb1T_k<<<24, 256, 0, stream>>>(bt1, idx_a2w, b1pT);
    sigb_k<<<24, 256, 0, stream>>>(bt2, idx_w2a, b2p);
    tcvt_k<<<216, 256, 0, stream>>>(qkv_w, Ws_t, 192, 288, 576, 288);
    tcvt_k<<<72, 256, 0, stream>>>(na_after_w, Waft_t, 192, 96, 96, 0);
    tcvt_k<<<144, 256, 0, stream>>>(proj_w, Wproj_t, 192, 192, 192, 0);
    cvt_bf16_k<<<6144, 256, 0, stream>>>(x, xb, 65536 * 192 / 8);

    // Stripe qkv: xb @ Ws_t^T + b -> qkvs bf16 (65536,288), row-major
    mfma_gemm_k<192, 0, bf16_t><<<dim3(3, 512), 256, 0, stream>>>(
        xb, Ws_t, qkv_b + 288, qkvs, 192, 192, 288);

    // Folded NA qkv: xb @ Wna_t^T + bna -> naqkv bf16 parity-split planes
    mfma_gemm_k<192, 1, bf16_t><<<dim3(6, 512), 256, 0, stream>>>(
        xb, Wna_t, bna, naqkv, 192, 192, 576);

    // Anchor: depthwise conv (xb dead -> adw in R), pointwise GEMM -> apw
    dwconv_k<<<3072, 256, 0, stream>>>(x, adw_w, adw_b, adw);
    gemm_k<float, float><<<dim3(2, 256), 256, 0, stream>>>(
        adw, apw_w, apw_b, apw, 16384, 96, 192, 192, 96, 96);

    // Neighborhood attention (adw dead -> xna_pre in R)
    na_attn_k<<<dim3(2, 128, 24), 256, 0, stream>>>(naqkv, na_rpb, xna_pre);

    // na_after: xna_pre @ Waft_t^T + b -> cat[:,0:96]  (naqkv dead)
    mfma_gemm_k<192, 0, bf16_t><<<dim3(1, 512), 256, 0, stream>>>(
        xna_pre, Waft_t, na_after_b, cat, 192, 192, 192);

    // Stripe attention -> x1, then cat[:,96:192]
    attn1_k<<<dim3(256, 6), 256, 0, stream>>>(apw, qkvs, b1pT, ls1, x1);
    attn2_k<<<1536, 256, 0, stream>>>(apw, qkvs, b2p, ls2, x1, cat);

    // Final projection: cat @ Wproj_t^T + proj_b -> out fp32
    mfma_gemm_k<192, 0, float><<<dim3(2, 512), 256, 0, stream>>>(
        cat, Wproj_t, proj_b, out, 192, 192, 192);
}